// Round 9
// baseline (932.315 us; speedup 1.0000x reference)
//
#include <hip/hip_runtime.h>
#include <math.h>

typedef _Float16 half8 __attribute__((ext_vector_type(8)));
typedef _Float16 half4t __attribute__((ext_vector_type(4)));
typedef float floatx4 __attribute__((ext_vector_type(4)));

// ============================================================================
// ConvDesc: geometry for implicit-GEMM conv (enc: stride-2 conv; dec: convT
// decomposed into 4 output-parity classes, each a uniform GEMM).
// ============================================================================
struct ConvDesc {
  int HI, WI;
  int CIs;
  int OYs, OXs;
  int SXY;
  int osxy;
  int HO, WO;
  int CO_pad, CO_real, CO_store;
  int nclass;
  int py[4], px[4], nt[4];
  int tt[4][9], tdy[4][9], tdx[4][9];
};

// ============================================================================
// conv_gemm<BM,BN>: 256 threads = 4 waves in 2x2; wave tile (BM/2)x(BN/2) of
// 16x16x32 f16 MFMAs. Double-buffered LDS K-loop: stage(k+1) issued before
// compute(k), one barrier/iter, so next-tile global loads overlap MFMA.
// As pitch-padded (+8 halfs) to break the 4KB-aligned 4-way write conflict.
// ============================================================================
template<int BM, int BN>
__global__ __launch_bounds__(256) void conv_gemm(
    const _Float16* __restrict__ act, const _Float16* __restrict__ wB,
    const float* __restrict__ bias, _Float16* __restrict__ y, ConvDesc d)
{
  constexpr int WM = BM / 2, WN = BN / 2, FM = WM / 16, FN = WN / 16;
  constexpr int ARPT = BM / 64, BT = BN / 64;
  constexpr int AP = BM * 8 + 8;      // padded q/fr pitch (halfs)
  constexpr int ASZ = 4 * AP;         // one A buffer (halfs)
  constexpr int BSZ = BT * 2048;      // one B buffer (halfs)
  __shared__ _Float16 As[2 * ASZ];
  __shared__ _Float16 Bs[2 * BSZ];

  const int tid = threadIdx.x;
  const int cls = blockIdx.z;
  const int m0 = blockIdx.x * BM, n0 = blockIdx.y * BN;
  const int q = tid & 3, r0 = tid >> 2;

  int aih[ARPT], aiw[ARPT], abase[ARPT];
  #pragma unroll
  for (int i = 0; i < ARPT; i++) {
    int p = m0 + r0 + i * 64;
    int n  = p >> (d.OYs + d.OXs);
    int oy = (p >> d.OXs) & ((1 << d.OYs) - 1);
    int ox = p & ((1 << d.OXs) - 1);
    aih[i] = oy * d.SXY;
    aiw[i] = ox * d.SXY;
    abase[i] = n * d.HI;
  }

  floatx4 acc[FM][FN] = {};
  const int wv = tid >> 6, lane = tid & 63;
  const int wm = wv >> 1, wn = wv & 1;
  const int fr = lane >> 4, fc = lane & 15;
  const int c5s = d.CIs - 5;
  const int c5m = (1 << c5s) - 1;
  const int kiters = d.nt[cls] << c5s;

  auto stageK = [&](int kk, int buf) {
    int ti = kk >> c5s, c5 = kk & c5m;
    int dy = d.tdy[cls][ti], dx = d.tdx[cls][ti];
    int kt0 = d.tt[cls][ti] << c5s;
    int c0 = c5 << 5;
    #pragma unroll
    for (int i = 0; i < ARPT; i++) {
      int ih = aih[i] + dy, iw = aiw[i] + dx;
      half8 v = {};
      if ((unsigned)ih < (unsigned)d.HI && (unsigned)iw < (unsigned)d.WI)
        v = *(const half8*)(act + ((((size_t)(abase[i] + ih)) * d.WI + iw) << d.CIs) + c0 + q * 8);
      *(half8*)(As + buf * ASZ + q * AP + (r0 + i * 64) * 8) = v;
    }
    #pragma unroll
    for (int j = 0; j < BT; j++) {
      const _Float16* src = wB + (size_t)((kt0 + c5) * (d.CO_pad >> 6) + (n0 >> 6) + j) * 2048 + tid * 8;
      *(half8*)(Bs + buf * BSZ + j * 2048 + tid * 8) = *(const half8*)src;
    }
  };

  stageK(0, 0);
  for (int kk = 0; kk < kiters; kk++) {
    __syncthreads();
    if (kk + 1 < kiters) stageK(kk + 1, (kk + 1) & 1);
    const int buf = kk & 1;
    half8 af[FM], bf[FN];
    #pragma unroll
    for (int a = 0; a < FM; a++)
      af[a] = *(const half8*)(As + buf * ASZ + fr * AP + (wm * WM + a * 16 + fc) * 8);
    #pragma unroll
    for (int b = 0; b < FN; b++) {
      int col = wn * WN + b * 16 + fc;
      bf[b] = *(const half8*)(Bs + buf * BSZ + (col >> 6) * 2048 + fr * 512 + (col & 63) * 8);
    }
    #pragma unroll
    for (int a = 0; a < FM; a++)
      #pragma unroll
      for (int b = 0; b < FN; b++)
        acc[a][b] = __builtin_amdgcn_mfma_f32_16x16x32_f16(af[a], bf[b], acc[a][b], 0, 0, 0);
  }

  float bv[FN];
  int colg[FN];
  #pragma unroll
  for (int b = 0; b < FN; b++) {
    int col = n0 + wn * WN + b * 16 + fc;
    colg[b] = col;
    bv[b] = (col < d.CO_real) ? bias[col] : 0.f;
  }
  const int pyc = d.py[cls], pxc = d.px[cls];
  #pragma unroll
  for (int a = 0; a < FM; a++) {
    #pragma unroll
    for (int rr = 0; rr < 4; rr++) {
      int m = m0 + wm * WM + a * 16 + fr * 4 + rr;
      int n  = m >> (d.OYs + d.OXs);
      int oy = (m >> d.OXs) & ((1 << d.OYs) - 1);
      int ox = m & ((1 << d.OXs) - 1);
      size_t opix = ((size_t)(n * d.HO + oy * d.osxy + pyc)) * d.WO + ox * d.osxy + pxc;
      _Float16* dst = y + opix * d.CO_store;
      #pragma unroll
      for (int b = 0; b < FN; b++)
        if (colg[b] < d.CO_store)
          dst[colg[b]] = (_Float16)(acc[a][b][rr] + bv[b]);
    }
  }
}

// ============================================================================
// dec3_fused: ConvT 64ch -> 4ch (real 3), input (16,128,128,64) NHWC,
// output (16,256,256,4). One block = 2x128 input strip; 3x129 halo patch in
// LDS serves all 9 taps / 4 parity classes; weights (18KB) staged once.
// ============================================================================
__global__ __launch_bounds__(256) void dec3_fused(
    const _Float16* __restrict__ act, const _Float16* __restrict__ wB,
    const float* __restrict__ bias, _Float16* __restrict__ y)
{
  __shared__ _Float16 As[4 * 3168];   // [kg4][slot 3*132][8]
  __shared__ _Float16 Bs[9216];
  const int tid = threadIdx.x;
  const int n = blockIdx.x >> 6;
  const int y0 = (blockIdx.x & 63) << 1;
  const int wv = tid >> 6, lane = tid & 63;
  const int fr = lane >> 4, fc = lane & 15;

  for (int i = tid; i < 1152; i += 256)
    *(half8*)(Bs + i * 8) = *(const half8*)(wB + i * 8);

  floatx4 acc[4][4] = {};   // [cls][a]

  for (int c5 = 0; c5 < 2; c5++) {
    __syncthreads();
    for (int i = tid; i < 1584; i += 256) {
      int slot = i >> 2, q = i & 3;
      int prow = slot / 132, pcol = slot - prow * 132;
      int row = y0 + prow;
      half8 v = {};
      if (row < 128 && pcol < 128)
        v = *(const half8*)(act + (((size_t)(n * 128 + row)) * 128 + pcol) * 64 + c5 * 32 + q * 8);
      *(half8*)(As + q * 3168 + slot * 8) = v;
    }
    __syncthreads();
    #pragma unroll
    for (int t = 0; t < 9; t++) {
      const int ky = t / 3, kx = t % 3;
      const int dy = (ky == 0) ? 1 : 0, dx = (kx == 0) ? 1 : 0;
      const int cls = ((ky + 1) & 1) * 2 + ((kx + 1) & 1);
      half8 bf = *(const half8*)(Bs + (t * 2 + c5) * 512 + fr * 128 + fc * 8);
      #pragma unroll
      for (int a = 0; a < 4; a++) {
        int m = wv * 64 + a * 16 + fc;
        int r = m >> 7, xx = m & 127;
        half8 af = *(const half8*)(As + fr * 3168 + ((r + dy) * 132 + xx + dx) * 8);
        acc[cls][a] = __builtin_amdgcn_mfma_f32_16x16x32_f16(af, bf, acc[cls][a], 0, 0, 0);
      }
    }
  }

  float bv = (fc < 3) ? bias[fc] : 0.f;
  if (fc < 4) {
    #pragma unroll
    for (int cls = 0; cls < 4; cls++) {
      int py = cls >> 1, px = cls & 1;
      #pragma unroll
      for (int a = 0; a < 4; a++) {
        #pragma unroll
        for (int rr = 0; rr < 4; rr++) {
          int m = wv * 64 + a * 16 + fr * 4 + rr;
          int r = m >> 7, xx = m & 127;
          size_t opix = ((size_t)(n * 256 + (y0 + r) * 2 + py)) * 256 + xx * 2 + px;
          y[opix * 4 + fc] = (_Float16)(acc[cls][a][rr] + bv);
        }
      }
    }
  }
}

// ============================================================================
// VQ GEMM (As pitch-padded)
// ============================================================================
__global__ __launch_bounds__(256) void vq_gemm(const _Float16* __restrict__ h,
    const _Float16* __restrict__ embB, const float* __restrict__ ee,
    float* __restrict__ minval, int* __restrict__ minidx)
{
  __shared__ char smem[32768];
  _Float16* As = (_Float16*)smem;            // 4 * 1032 halfs
  _Float16* Bs = (_Float16*)(smem + 8448);   // 4096 halfs
  const int tid = threadIdx.x;
  const int m0 = blockIdx.x * 128, n0 = blockIdx.y * 128;
  const int q = tid & 3, r0 = tid >> 2;
  floatx4 acc[4][4] = {};
  const int wv = tid >> 6, lane = tid & 63;
  const int wm = wv >> 1, wn = wv & 1;
  const int fr = lane >> 4, fc = lane & 15;

  for (int c5 = 0; c5 < 16; c5++) {
    #pragma unroll
    for (int i = 0; i < 2; i++) {
      half8 v = *(const half8*)(h + (size_t)(m0 + r0 + i * 64) * 512 + c5 * 32 + q * 8);
      *(half8*)(As + q * 1032 + (r0 + i * 64) * 8) = v;
    }
    #pragma unroll
    for (int j = 0; j < 2; j++)
      *(half8*)(Bs + j * 2048 + tid * 8) =
          *(const half8*)(embB + (size_t)(c5 * 32 + (n0 >> 6) + j) * 2048 + tid * 8);
    __syncthreads();
    half8 af[4], bf[4];
    #pragma unroll
    for (int a = 0; a < 4; a++)
      af[a] = *(const half8*)(As + fr * 1032 + (wm * 64 + a * 16 + fc) * 8);
    #pragma unroll
    for (int b = 0; b < 4; b++) {
      int col = wn * 64 + b * 16 + fc;
      bf[b] = *(const half8*)(Bs + (col >> 6) * 2048 + fr * 512 + (col & 63) * 8);
    }
    #pragma unroll
    for (int a = 0; a < 4; a++)
      #pragma unroll
      for (int b = 0; b < 4; b++)
        acc[a][b] = __builtin_amdgcn_mfma_f32_16x16x32_f16(af[a], bf[b], acc[a][b], 0, 0, 0);
    __syncthreads();
  }

  float* sval = (float*)smem;
  int*   sidx = (int*)(smem + 16384);
  #pragma unroll
  for (int a = 0; a < 4; a++) {
    #pragma unroll
    for (int rr = 0; rr < 4; rr++) {
      int rb = wm * 64 + a * 16 + fr * 4 + rr;
      float best = 1e30f; int bi = 0;
      #pragma unroll
      for (int b = 0; b < 4; b++) {
        int e = n0 + wn * 64 + b * 16 + fc;
        float s = ee[e] - 2.f * acc[a][b][rr];
        if (s < best) { best = s; bi = e; }
      }
      sval[rb * 32 + wn * 16 + fc] = best;
      sidx[rb * 32 + wn * 16 + fc] = bi;
    }
  }
  __syncthreads();
  if (tid < 128) {
    float best = sval[tid * 32]; int bi = sidx[tid * 32];
    for (int t = 1; t < 32; t++) {
      float v = sval[tid * 32 + t]; int ix = sidx[tid * 32 + t];
      if (v < best || (v == best && ix < bi)) { best = v; bi = ix; }
    }
    minval[(size_t)(m0 + tid) * 16 + blockIdx.y] = best;
    minidx[(size_t)(m0 + tid) * 16 + blockIdx.y] = bi;
  }
}

__global__ __launch_bounds__(256) void vq_finalize(const _Float16* __restrict__ h,
    const float* __restrict__ emb, const float* __restrict__ minval,
    const int* __restrict__ minidx, float* __restrict__ lossacc)
{
  const int tid = threadIdx.x;
  const int g = tid >> 4, l = tid & 15;
  const int v = blockIdx.x * 16 + g;
  float val = minval[(size_t)v * 16 + l];
  int   idx = minidx[(size_t)v * 16 + l];
  #pragma unroll
  for (int o = 8; o > 0; o >>= 1) {
    float v2 = __shfl_down(val, o, 16);
    int   i2 = __shfl_down(idx, o, 16);
    if (v2 < val || (v2 == val && i2 < idx)) { val = v2; idx = i2; }
  }
  idx = __shfl(idx, 0, 16);
  float s = 0.f;
  #pragma unroll
  for (int j = 0; j < 32; j++) {
    int c = l + 16 * j;
    float f = (float)h[(size_t)v * 512 + c];
    float e = emb[(size_t)idx * 512 + c];
    float dd = f - e;
    s += dd * dd;
  }
  #pragma unroll
  for (int o = 8; o > 0; o >>= 1) s += __shfl_down(s, o, 16);
  if (l == 0) atomicAdd(lossacc, s);
}

// ============================================================================
// BN stats — vectorized two-stage reduce.
// ============================================================================
__global__ __launch_bounds__(256) void bn_stats_fast(const _Float16* __restrict__ y,
    float2* __restrict__ part, int Cs, int perblk)
{
  const int C = 1 << Cs;
  const int Cp = (C < 8) ? 8 : C;
  const int G = Cp >> 3;
  const int tid = threadIdx.x;
  const size_t base = (size_t)blockIdx.x * perblk;
  const int iters = perblk >> 8;

  float s[8] = {}, qq[8] = {};
  for (int k = 0; k < iters; k++) {
    half8 v = *(const half8*)(y + ((base + tid + (size_t)k * 256) << 3));
    #pragma unroll
    for (int j = 0; j < 8; j++) { float f = (float)v[j]; s[j] += f; qq[j] += f * f; }
  }

  __shared__ float2 red[256 * 8];
  #pragma unroll
  for (int j = 0; j < 8; j++) red[tid * 8 + j] = make_float2(s[j], qq[j]);
  __syncthreads();
  for (int off = 128; off >= G; off >>= 1) {
    if (tid < off) {
      #pragma unroll
      for (int j = 0; j < 8; j++) {
        float2 o = red[(tid + off) * 8 + j];
        float2 m = red[tid * 8 + j];
        red[tid * 8 + j] = make_float2(m.x + o.x, m.y + o.y);
      }
    }
    __syncthreads();
  }
  if (tid < G) {
    #pragma unroll
    for (int j = 0; j < 8; j++)
      part[(size_t)blockIdx.x * Cp + tid * 8 + j] = red[tid * 8 + j];
  }
}

__global__ __launch_bounds__(256) void bn_stats2_fast(const float2* __restrict__ part,
    const float* __restrict__ g, const float* __restrict__ be,
    float* __restrict__ sc, float* __restrict__ sh,
    int C, int C_real, int NB, float invM)
{
  const int Cp = (C < 8) ? 8 : C;
  const int cl = threadIdx.x & 63, grp = threadIdx.x >> 6;
  const int c = blockIdx.x * 64 + cl;
  float s = 0.f, q = 0.f;
  if (c < Cp) {
    for (int i = grp; i < NB; i += 4) {
      float2 v = part[(size_t)i * Cp + c];
      s += v.x; q += v.y;
    }
  }
  __shared__ float rs[4][64], rq[4][64];
  rs[grp][cl] = s; rq[grp][cl] = q;
  __syncthreads();
  if (grp == 0 && c < C) {
    float st = rs[0][cl] + rs[1][cl] + rs[2][cl] + rs[3][cl];
    float qt = rq[0][cl] + rq[1][cl] + rq[2][cl] + rq[3][cl];
    if (C < 8) {
      st += rs[0][cl + C] + rs[1][cl + C] + rs[2][cl + C] + rs[3][cl + C];
      qt += rq[0][cl + C] + rq[1][cl + C] + rq[2][cl + C] + rq[3][cl + C];
    }
    float m = st * invM, var = qt * invM - m * m;
    float gg = (c < C_real) ? g[c] : 1.f;
    float bb = (c < C_real) ? be[c] : 0.f;
    float scale = gg * rsqrtf(var + 1e-5f);
    sc[c] = scale; sh[c] = bb - m * scale;
  }
}

__global__ __launch_bounds__(256) void bn_apply(_Float16* __restrict__ y,
    const float* __restrict__ sc, const float* __restrict__ sh, int Cs, int n8)
{
  int i = blockIdx.x * 256 + threadIdx.x;
  if (i >= n8) return;
  int c0 = (i << 3) & ((1 << Cs) - 1);
  half8 v = *(half8*)(y + (size_t)i * 8);
  half8 o;
  #pragma unroll
  for (int j = 0; j < 8; j++) {
    float x = (float)v[j] * sc[c0 + j] + sh[c0 + j];
    o[j] = (_Float16)(0.5f * x * (1.f + erff(x * 0.70710678118654752f)));
  }
  *(half8*)(y + (size_t)i * 8) = o;
}

__global__ __launch_bounds__(256) void bn_final(const _Float16* __restrict__ y,
    float* __restrict__ out, const float* __restrict__ sc, const float* __restrict__ sh,
    const float* __restrict__ lossacc)
{
  int p = blockIdx.x * 256 + threadIdx.x;
  int n = p >> 16, hw = p & 65535;
  half4t v = *(const half4t*)(y + (size_t)p * 4);
  #pragma unroll
  for (int c = 0; c < 3; c++) {
    float x = (float)v[c] * sc[c] + sh[c];
    float gg = 0.5f * x * (1.f + erff(x * 0.70710678118654752f));
    out[(size_t)(n * 3 + c) * 65536 + hw] = tanhf(gg);
  }
  if (p == 0) out[3145728] = lossacc[0] * (1.25f / 2097152.0f);
}

// ============================================================================
// layout transforms
// ============================================================================
__global__ __launch_bounds__(256) void im2col_enc0(const float* __restrict__ x,
                                                   _Float16* __restrict__ xp)
{
  int p = blockIdx.x * 256 + threadIdx.x;      // 262144 output pixels
  int n = p >> 14, oy = (p >> 7) & 127, ox = p & 127;
  const float* xb = x + (size_t)n * 3 * 65536;
  _Float16 v[32];
  #pragma unroll
  for (int k = 27; k < 32; k++) v[k] = (_Float16)0.f;
  #pragma unroll
  for (int tap = 0; tap < 9; tap++) {
    int kh = tap / 3, kw = tap - kh * 3;
    int ih = 2 * oy - 1 + kh, iw = 2 * ox - 1 + kw;
    bool ok = ((unsigned)ih < 256u) && ((unsigned)iw < 256u);
    #pragma unroll
    for (int c = 0; c < 3; c++)
      v[tap * 3 + c] = ok ? (_Float16)xb[(size_t)c * 65536 + ih * 256 + iw] : (_Float16)0.f;
  }
  _Float16* dst = xp + (size_t)p * 32;
  #pragma unroll
  for (int j = 0; j < 4; j++) *(half8*)(dst + j * 8) = *(half8*)(v + j * 8);
}

__global__ void wtrans0(const float* __restrict__ w, _Float16* __restrict__ wB)
{
  int idx = blockIdx.x * 256 + threadIdx.x;   // 2048 = 32*64
  if (idx >= 2048) return;
  int k = idx >> 6, co = idx & 63;
  int tap = k / 3, c = k - tap * 3;
  float v = (k < 27) ? w[((size_t)co * 3 + c) * 9 + tap] : 0.f;
  int kg = (k >> 3) & 3, kj = k & 7;
  wB[kg * 512 + co * 8 + kj] = (_Float16)v;
}

// dec3 weights: K=576 (tap*64+ci), 16-col tiles [kt18][kg4][cc16][kj8].
// No kernel flip — gather-form tap algebra handles ConvT.
__global__ void wtrans_n16_dec3(const float* __restrict__ w, _Float16* __restrict__ wB)
{
  int idx = blockIdx.x * 256 + threadIdx.x;   // 9216 = 576*16
  if (idx >= 9216) return;
  int k = idx >> 4, co = idx & 15;
  int tap = k >> 6, ci = k & 63;
  float v = 0.f;
  if (co < 3) v = w[((size_t)ci * 3 + co) * 9 + tap];
  int kt = k >> 5, kg = (k >> 3) & 3, kj = k & 7;
  wB[(size_t)kt * 512 + kg * 128 + co * 8 + kj] = (_Float16)v;
}

__global__ __launch_bounds__(256) void wtrans(const float* __restrict__ w,
    _Float16* __restrict__ wB, int CIs, int CI_real, int COs, int CO_real, int is_dec)
{
  int idx = blockIdx.x * 256 + threadIdx.x;
  int CO_pad = 1 << COs;
  int K = 9 << CIs;
  if (idx >= K * CO_pad) return;
  int k = idx >> COs, co = idx & (CO_pad - 1);
  int tap = k >> CIs, ci = k & ((1 << CIs) - 1);
  int kh = tap / 3, kw = tap - kh * 3;
  float v = 0.f;
  if (ci < CI_real && co < CO_real)
    v = is_dec ? w[(((size_t)ci * CO_real + co) * 3 + kh) * 3 + kw]
               : w[(((size_t)co * CI_real + ci) * 3 + kh) * 3 + kw];
  int kt = k >> 5, kg = (k >> 3) & 3, kj = k & 7, jt = co >> 6, cc = co & 63;
  wB[(size_t)(kt * (CO_pad >> 6) + jt) * 2048 + kg * 512 + cc * 8 + kj] = (_Float16)v;
}

__global__ __launch_bounds__(256) void embtrans(const float* __restrict__ emb,
                                                _Float16* __restrict__ embB)
{
  int idx = blockIdx.x * 256 + threadIdx.x;
  int k = idx >> 11, e = idx & 2047;
  float v = emb[(size_t)e * 512 + k];
  int kt = k >> 5, kg = (k >> 3) & 3, kj = k & 7, jt = e >> 6, cc = e & 63;
  embB[(size_t)(kt * 32 + jt) * 2048 + kg * 512 + cc * 8 + kj] = (_Float16)v;
}

__global__ __launch_bounds__(256) void emb_norms(const float* __restrict__ emb,
                                                 float* __restrict__ ee)
{
  const int wv = threadIdx.x >> 6, lane = threadIdx.x & 63;
  const int e = blockIdx.x * 4 + wv;
  float s = 0.f;
  #pragma unroll
  for (int j = 0; j < 8; j++) { float v = emb[(size_t)e * 512 + lane + j * 64]; s += v * v; }
  for (int o = 32; o > 0; o >>= 1) s += __shfl_down(s, o);
  if (lane == 0) ee[e] = s;
}

__global__ void zero_loss(float* p) { p[0] = 0.f; }

// ============================================================================
// host
// ============================================================================
static ConvDesc enc_desc(int HI, int WI, int CIs, int CO) {
  ConvDesc d = {};
  d.HI = HI; d.WI = WI; d.CIs = CIs;
  int HO = HI / 2, WO = WI / 2;
  d.OYs = __builtin_ctz(HO); d.OXs = __builtin_ctz(WO);
  d.SXY = 2; d.osxy = 1; d.HO = HO; d.WO = WO;
  d.CO_pad = CO; d.CO_real = CO; d.CO_store = CO;
  d.nclass = 1; d.py[0] = 0; d.px[0] = 0; d.nt[0] = 9;
  for (int t = 0; t < 9; t++) { d.tt[0][t] = t; d.tdy[0][t] = t / 3 - 1; d.tdx[0][t] = t % 3 - 1; }
  return d;
}

static ConvDesc dec_desc(int HI, int WI, int CIs, int CO_pad, int CO_real, int CO_store) {
  ConvDesc d = {};
  d.HI = HI; d.WI = WI; d.CIs = CIs;
  d.OYs = __builtin_ctz(HI); d.OXs = __builtin_ctz(WI);
  d.SXY = 1; d.osxy = 2; d.HO = 2 * HI; d.WO = 2 * WI;
  d.CO_pad = CO_pad; d.CO_real = CO_real; d.CO_store = CO_store;
  d.nclass = 4;
  int kys[2][2] = {{1, -1}, {0, 2}}, dis[2][2] = {{0, -1}, {1, 0}}, cnt[2] = {1, 2};
  for (int py = 0; py < 2; py++)
    for (int px = 0; px < 2; px++) {
      int c = py * 2 + px; d.py[c] = py; d.px[c] = px;
      int m = 0;
      for (int a = 0; a < cnt[py]; a++)
        for (int b = 0; b < cnt[px]; b++) {
          d.tt[c][m] = kys[py][a] * 3 + kys[px][b];
          d.tdy[c][m] = dis[py][a]; d.tdx[c][m] = dis[px][b]; m++;
        }
      d.nt[c] = m;
    }
  return d;
}

extern "C" void kernel_launch(void* const* d_in, const int* in_sizes, int n_in,
                              void* d_out, int out_size, void* d_ws, size_t ws_size,
                              hipStream_t stream)
{
  const float* x = (const float*)d_in[0];
  const float *ew[4], *ebi[4], *eg[4], *ebe[4];
  const float *dw[4], *dbi[4], *dg[4], *dbe[4];
  for (int i = 0; i < 4; i++) {
    ew[i]  = (const float*)d_in[1 + 4 * i];
    ebi[i] = (const float*)d_in[2 + 4 * i];
    eg[i]  = (const float*)d_in[3 + 4 * i];
    ebe[i] = (const float*)d_in[4 + 4 * i];
    dw[i]  = (const float*)d_in[17 + 4 * i];
    dbi[i] = (const float*)d_in[18 + 4 * i];
    dg[i]  = (const float*)d_in[19 + 4 * i];
    dbe[i] = (const float*)d_in[20 + 4 * i];
  }
  const float* emb = (const float*)d_in[33];
  float* out = (float*)d_out;
  _Float16* wsh = (_Float16*)d_ws;

  // memory map (halfs)
  _Float16* bufA = wsh;
  _Float16* xp   = wsh;                       // im2col rows: 262144*32 = 8.4M halfs
  _Float16* bufB = wsh + 33554432;
  size_t wboff = 50331648;
  _Float16* wbE[4], *wbD[4];
  size_t wbsz[8] = {18432, 73728, 294912, 1179648, 1179648, 294912, 73728, 36864};
  for (int i = 0; i < 4; i++) { wbE[i] = wsh + wboff; wboff += wbsz[i]; }
  for (int i = 0; i < 4; i++) { wbD[i] = wsh + wboff; wboff += wbsz[4 + i]; }
  _Float16* embB = wsh + wboff;               // ends 54,532,096
  float* f32 = (float*)(wsh + 54532096);
  float2* part  = (float2*)f32;
  float* sc     = f32 + 524288;
  float* sh     = f32 + 524800;
  float* ee     = f32 + 525312;
  float* minval = f32 + 527360;
  int*   minidx = (int*)(f32 + 592896);
  float* lossacc= f32 + 658432;

  // ---- transforms ----
  im2col_enc0<<<1024, 256, 0, stream>>>(x, xp);
  wtrans0<<<8, 256, 0, stream>>>(ew[0], wbE[0]);
  wtrans<<<288, 256, 0, stream>>>(ew[1], wbE[1], 6, 64, 7, 128, 0);
  wtrans<<<1152, 256, 0, stream>>>(ew[2], wbE[2], 7, 128, 8, 256, 0);
  wtrans<<<4608, 256, 0, stream>>>(ew[3], wbE[3], 8, 256, 9, 512, 0);
  wtrans<<<4608, 256, 0, stream>>>(dw[0], wbD[0], 9, 512, 8, 256, 1);
  wtrans<<<1152, 256, 0, stream>>>(dw[1], wbD[1], 8, 256, 7, 128, 1);
  wtrans<<<288, 256, 0, stream>>>(dw[2], wbD[2], 7, 128, 6, 64, 1);
  wtrans_n16_dec3<<<36, 256, 0, stream>>>(dw[3], wbD[3]);
  embtrans<<<4096, 256, 0, stream>>>(emb, embB);
  emb_norms<<<512, 256, 0, stream>>>(emb, ee);
  zero_loss<<<1, 1, 0, stream>>>(lossacc);

  auto bn = [&](_Float16* y, const float* g, const float* be, int Cs, int C_real, int P) {
    int C = 1 << Cs;
    int Cp = (C < 8) ? 8 : C;
    int n8 = (P << Cs) >> 3;
    int NB = n8 >> 11; if (NB > 512) NB = 512; if (NB < 1) NB = 1;
    int perblk = n8 / NB;
    bn_stats_fast<<<NB, 256, 0, stream>>>(y, part, Cs, perblk);
    bn_stats2_fast<<<(Cp + 63) / 64, 256, 0, stream>>>(part, g, be, sc, sh, C, C_real, NB, 1.f / (float)P);
  };

  // ---- encoder ----
  {
    // layer 0 as pure GEMM over im2col rows (K=32)
    ConvDesc d = {};
    d.HI = 512; d.WI = 512; d.CIs = 5; d.OYs = 9; d.OXs = 9; d.SXY = 1; d.osxy = 1;
    d.HO = 512; d.WO = 512; d.CO_pad = 64; d.CO_real = 64; d.CO_store = 64;
    d.nclass = 1; d.nt[0] = 1;  // tt/tdy/tdx = 0
    conv_gemm<128, 64><<<dim3(2048, 1, 1), 256, 0, stream>>>(xp, wbE[0], ebi[0], bufB, d);
    bn(bufB, eg[0], ebe[0], 6, 64, 262144);
    bn_apply<<<8192, 256, 0, stream>>>(bufB, sc, sh, 6, 2097152);
  }
  {
    ConvDesc d = enc_desc(128, 128, 6, 128);
    conv_gemm<128, 128><<<dim3(512, 1, 1), 256, 0, stream>>>(bufB, wbE[1], ebi[1], bufA, d);
    bn(bufA, eg[1], ebe[1], 7, 128, 65536);
    bn_apply<<<4096, 256, 0, stream>>>(bufA, sc, sh, 7, 1048576);
  }
  {
    // enc2 retiled to <128,64>: 512 blocks (2/CU) instead of 256
    ConvDesc d = enc_desc(64, 64, 7, 256);
    conv_gemm<128, 64><<<dim3(128, 4, 1), 256, 0, stream>>>(bufA, wbE[2], ebi[2], bufB, d);
    bn(bufB, eg[2], ebe[2], 8, 256, 16384);
    bn_apply<<<2048, 256, 0, stream>>>(bufB, sc, sh, 8, 524288);
  }
  {
    ConvDesc d = enc_desc(32, 32, 8, 512);
    conv_gemm<64, 64><<<dim3(64, 8, 1), 256, 0, stream>>>(bufB, wbE[3], ebi[3], bufA, d);
    bn(bufA, eg[3], ebe[3], 9, 512, 4096);
    bn_apply<<<1024, 256, 0, stream>>>(bufA, sc, sh, 9, 262144);
  }
  _Float16* h = bufA;  // (16,16,16,512) NHWC

  // ---- VQ ----
  vq_gemm<<<dim3(32, 16), 256, 0, stream>>>(h, embB, ee, minval, minidx);
  vq_finalize<<<256, 256, 0, stream>>>(h, emb, minval, minidx, lossacc);

  // ---- decoder ----
  {
    ConvDesc d = dec_desc(16, 16, 9, 256, 256, 256);
    conv_gemm<64, 64><<<dim3(64, 4, 4), 256, 0, stream>>>(h, wbD[0], dbi[0], bufB, d);
    bn(bufB, dg[0], dbe[0], 8, 256, 16384);
    bn_apply<<<2048, 256, 0, stream>>>(bufB, sc, sh, 8, 524288);
  }
  {
    ConvDesc d = dec_desc(32, 32, 8, 128, 128, 128);
    conv_gemm<128, 128><<<dim3(128, 1, 4), 256, 0, stream>>>(bufB, wbD[1], dbi[1], bufA, d);
    bn(bufA, dg[1], dbe[1], 7, 128, 65536);
    bn_apply<<<4096, 256, 0, stream>>>(bufA, sc, sh, 7, 1048576);
  }
  {
    ConvDesc d = dec_desc(64, 64, 7, 64, 64, 64);
    conv_gemm<128, 64><<<dim3(512, 1, 4), 256, 0, stream>>>(bufA, wbD[2], dbi[2], bufB, d);
    bn(bufB, dg[2], dbe[2], 6, 64, 262144);
    bn_apply<<<8192, 256, 0, stream>>>(bufB, sc, sh, 6, 2097152);
  }
  {
    dec3_fused<<<1024, 256, 0, stream>>>(bufB, wbD[3], dbi[3], bufA);
    bn(bufA, dg[3], dbe[3], 2, 3, 1048576);
    bn_final<<<4096, 256, 0, stream>>>(bufA, out, sc, sh, lossacc);
  }
}

// Round 10
// 695.975 us; speedup vs baseline: 1.3396x; 1.3396x over previous
//
#include <hip/hip_runtime.h>
#include <math.h>

typedef _Float16 half8 __attribute__((ext_vector_type(8)));
typedef _Float16 half4t __attribute__((ext_vector_type(4)));
typedef float floatx4 __attribute__((ext_vector_type(4)));

// ============================================================================
// ConvDesc
// ============================================================================
struct ConvDesc {
  int HI, WI;
  int CIs;
  int OYs, OXs;
  int SXY;
  int osxy;
  int HO, WO;
  int CO_pad, CO_real, CO_store;
  int nclass;
  int py[4], px[4], nt[4];
  int tt[4][9], tdy[4][9], tdx[4][9];
};

#define STAT_SLOTS 16

// ============================================================================
// conv_gemm<BM,BN>: dbuf K-loop + fused BN-stats epilogue (per-column
// sum/sumsq reduced in LDS, atomicAdd into 16-slot-spread stats buffer).
// ============================================================================
template<int BM, int BN>
__global__ __launch_bounds__(256) void conv_gemm(
    const _Float16* __restrict__ act, const _Float16* __restrict__ wB,
    const float* __restrict__ bias, _Float16* __restrict__ y,
    float* __restrict__ stats, ConvDesc d)
{
  constexpr int WM = BM / 2, WN = BN / 2, FM = WM / 16, FN = WN / 16;
  constexpr int ARPT = BM / 64, BT = BN / 64;
  constexpr int AP = BM * 8 + 8;
  constexpr int ASZ = 4 * AP;
  constexpr int BSZ = BT * 2048;
  __shared__ __align__(16) _Float16 As[2 * ASZ];
  __shared__ __align__(16) _Float16 Bs[2 * BSZ];

  const int tid = threadIdx.x;
  const int cls = blockIdx.z;
  const int m0 = blockIdx.x * BM, n0 = blockIdx.y * BN;
  const int q = tid & 3, r0 = tid >> 2;

  int aih[ARPT], aiw[ARPT], abase[ARPT];
  #pragma unroll
  for (int i = 0; i < ARPT; i++) {
    int p = m0 + r0 + i * 64;
    int n  = p >> (d.OYs + d.OXs);
    int oy = (p >> d.OXs) & ((1 << d.OYs) - 1);
    int ox = p & ((1 << d.OXs) - 1);
    aih[i] = oy * d.SXY;
    aiw[i] = ox * d.SXY;
    abase[i] = n * d.HI;
  }

  floatx4 acc[FM][FN] = {};
  const int wv = tid >> 6, lane = tid & 63;
  const int wm = wv >> 1, wn = wv & 1;
  const int fr = lane >> 4, fc = lane & 15;
  const int c5s = d.CIs - 5;
  const int c5m = (1 << c5s) - 1;
  const int kiters = d.nt[cls] << c5s;

  auto stageK = [&](int kk, int buf) {
    int ti = kk >> c5s, c5 = kk & c5m;
    int dy = d.tdy[cls][ti], dx = d.tdx[cls][ti];
    int kt0 = d.tt[cls][ti] << c5s;
    int c0 = c5 << 5;
    #pragma unroll
    for (int i = 0; i < ARPT; i++) {
      int ih = aih[i] + dy, iw = aiw[i] + dx;
      half8 v = {};
      if ((unsigned)ih < (unsigned)d.HI && (unsigned)iw < (unsigned)d.WI)
        v = *(const half8*)(act + ((((size_t)(abase[i] + ih)) * d.WI + iw) << d.CIs) + c0 + q * 8);
      *(half8*)(As + buf * ASZ + q * AP + (r0 + i * 64) * 8) = v;
    }
    #pragma unroll
    for (int j = 0; j < BT; j++) {
      const _Float16* src = wB + (size_t)((kt0 + c5) * (d.CO_pad >> 6) + (n0 >> 6) + j) * 2048 + tid * 8;
      *(half8*)(Bs + buf * BSZ + j * 2048 + tid * 8) = *(const half8*)src;
    }
  };

  stageK(0, 0);
  for (int kk = 0; kk < kiters; kk++) {
    __syncthreads();
    if (kk + 1 < kiters) stageK(kk + 1, (kk + 1) & 1);
    const int buf = kk & 1;
    half8 af[FM], bf[FN];
    #pragma unroll
    for (int a = 0; a < FM; a++)
      af[a] = *(const half8*)(As + buf * ASZ + fr * AP + (wm * WM + a * 16 + fc) * 8);
    #pragma unroll
    for (int b = 0; b < FN; b++) {
      int col = wn * WN + b * 16 + fc;
      bf[b] = *(const half8*)(Bs + buf * BSZ + (col >> 6) * 2048 + fr * 512 + (col & 63) * 8);
    }
    #pragma unroll
    for (int a = 0; a < FM; a++)
      #pragma unroll
      for (int b = 0; b < FN; b++)
        acc[a][b] = __builtin_amdgcn_mfma_f32_16x16x32_f16(af[a], bf[b], acc[a][b], 0, 0, 0);
  }

  float bv[FN];
  int colg[FN];
  #pragma unroll
  for (int b = 0; b < FN; b++) {
    int col = n0 + wn * WN + b * 16 + fc;
    colg[b] = col;
    bv[b] = (col < d.CO_real) ? bias[col] : 0.f;
  }
  float ssum[FN] = {}, ssq[FN] = {};
  const int pyc = d.py[cls], pxc = d.px[cls];
  #pragma unroll
  for (int a = 0; a < FM; a++) {
    #pragma unroll
    for (int rr = 0; rr < 4; rr++) {
      int m = m0 + wm * WM + a * 16 + fr * 4 + rr;
      int n  = m >> (d.OYs + d.OXs);
      int oy = (m >> d.OXs) & ((1 << d.OYs) - 1);
      int ox = m & ((1 << d.OXs) - 1);
      size_t opix = ((size_t)(n * d.HO + oy * d.osxy + pyc)) * d.WO + ox * d.osxy + pxc;
      _Float16* dst = y + opix * d.CO_store;
      #pragma unroll
      for (int b = 0; b < FN; b++) {
        float val = acc[a][b][rr] + bv[b];
        if (colg[b] < d.CO_store) dst[colg[b]] = (_Float16)val;
        ssum[b] += val; ssq[b] += val * val;
      }
    }
  }

  // fused BN stats: LDS reduce per column, atomic into slot-spread buffer
  __syncthreads();
  float2* red = (float2*)As;   // BN*8 float2 <= 8KB, fits in As
  #pragma unroll
  for (int b = 0; b < FN; b++)
    red[(wn * WN + b * 16 + fc) * 8 + wm * 4 + fr] = make_float2(ssum[b], ssq[b]);
  __syncthreads();
  if (tid < BN) {
    float s = 0.f, qv = 0.f;
    #pragma unroll
    for (int g2 = 0; g2 < 8; g2++) { float2 v = red[tid * 8 + g2]; s += v.x; qv += v.y; }
    int slot = (blockIdx.x + blockIdx.z) & (STAT_SLOTS - 1);
    float* sp = stats + ((size_t)(n0 + tid) * STAT_SLOTS + slot) * 2;
    atomicAdd(sp, s); atomicAdd(sp + 1, qv);
  }
}

// ============================================================================
// dec3_fused: ConvT 64ch -> 4ch (real 3) + fused stats epilogue.
// ============================================================================
__global__ __launch_bounds__(256) void dec3_fused(
    const _Float16* __restrict__ act, const _Float16* __restrict__ wB,
    const float* __restrict__ bias, _Float16* __restrict__ y,
    float* __restrict__ stats)
{
  __shared__ __align__(16) _Float16 As[4 * 3168];
  __shared__ __align__(16) _Float16 Bs[9216];
  const int tid = threadIdx.x;
  const int n = blockIdx.x >> 6;
  const int y0 = (blockIdx.x & 63) << 1;
  const int wv = tid >> 6, lane = tid & 63;
  const int fr = lane >> 4, fc = lane & 15;

  for (int i = tid; i < 1152; i += 256)
    *(half8*)(Bs + i * 8) = *(const half8*)(wB + i * 8);

  floatx4 acc[4][4] = {};

  for (int c5 = 0; c5 < 2; c5++) {
    __syncthreads();
    for (int i = tid; i < 1584; i += 256) {
      int slot = i >> 2, q = i & 3;
      int prow = slot / 132, pcol = slot - prow * 132;
      int row = y0 + prow;
      half8 v = {};
      if (row < 128 && pcol < 128)
        v = *(const half8*)(act + (((size_t)(n * 128 + row)) * 128 + pcol) * 64 + c5 * 32 + q * 8);
      *(half8*)(As + q * 3168 + slot * 8) = v;
    }
    __syncthreads();
    #pragma unroll
    for (int t = 0; t < 9; t++) {
      const int ky = t / 3, kx = t % 3;
      const int dy = (ky == 0) ? 1 : 0, dx = (kx == 0) ? 1 : 0;
      const int cls = ((ky + 1) & 1) * 2 + ((kx + 1) & 1);
      half8 bf = *(const half8*)(Bs + (t * 2 + c5) * 512 + fr * 128 + fc * 8);
      #pragma unroll
      for (int a = 0; a < 4; a++) {
        int m = wv * 64 + a * 16 + fc;
        int r = m >> 7, xx = m & 127;
        half8 af = *(const half8*)(As + fr * 3168 + ((r + dy) * 132 + xx + dx) * 8);
        acc[cls][a] = __builtin_amdgcn_mfma_f32_16x16x32_f16(af, bf, acc[cls][a], 0, 0, 0);
      }
    }
  }

  float bv = (fc < 3) ? bias[fc] : 0.f;
  float s4 = 0.f, q4 = 0.f;
  if (fc < 4) {
    #pragma unroll
    for (int cls = 0; cls < 4; cls++) {
      int py = cls >> 1, px = cls & 1;
      #pragma unroll
      for (int a = 0; a < 4; a++) {
        #pragma unroll
        for (int rr = 0; rr < 4; rr++) {
          int m = wv * 64 + a * 16 + fr * 4 + rr;
          int r = m >> 7, xx = m & 127;
          size_t opix = ((size_t)(n * 256 + (y0 + r) * 2 + py)) * 256 + xx * 2 + px;
          float val = acc[cls][a][rr] + bv;
          y[opix * 4 + fc] = (_Float16)val;
          s4 += val; q4 += val * val;
        }
      }
    }
  }
  __syncthreads();
  float2* red = (float2*)As;   // [4ch][16 groups]
  if (fc < 4) red[fc * 16 + wv * 4 + fr] = make_float2(s4, q4);
  __syncthreads();
  if (tid < 4) {
    float s = 0.f, qv = 0.f;
    #pragma unroll
    for (int g2 = 0; g2 < 16; g2++) { float2 v = red[tid * 16 + g2]; s += v.x; qv += v.y; }
    int slot = blockIdx.x & (STAT_SLOTS - 1);
    float* sp = stats + ((size_t)tid * STAT_SLOTS + slot) * 2;
    atomicAdd(sp, s); atomicAdd(sp + 1, qv);
  }
}

// ============================================================================
// VQ GEMM
// ============================================================================
__global__ __launch_bounds__(256) void vq_gemm(const _Float16* __restrict__ h,
    const _Float16* __restrict__ embB, const float* __restrict__ ee,
    float* __restrict__ minval, int* __restrict__ minidx)
{
  __shared__ char smem[32768];
  _Float16* As = (_Float16*)smem;
  _Float16* Bs = (_Float16*)(smem + 8448);
  const int tid = threadIdx.x;
  const int m0 = blockIdx.x * 128, n0 = blockIdx.y * 128;
  const int q = tid & 3, r0 = tid >> 2;
  floatx4 acc[4][4] = {};
  const int wv = tid >> 6, lane = tid & 63;
  const int wm = wv >> 1, wn = wv & 1;
  const int fr = lane >> 4, fc = lane & 15;

  for (int c5 = 0; c5 < 16; c5++) {
    #pragma unroll
    for (int i = 0; i < 2; i++) {
      half8 v = *(const half8*)(h + (size_t)(m0 + r0 + i * 64) * 512 + c5 * 32 + q * 8);
      *(half8*)(As + q * 1032 + (r0 + i * 64) * 8) = v;
    }
    #pragma unroll
    for (int j = 0; j < 2; j++)
      *(half8*)(Bs + j * 2048 + tid * 8) =
          *(const half8*)(embB + (size_t)(c5 * 32 + (n0 >> 6) + j) * 2048 + tid * 8);
    __syncthreads();
    half8 af[4], bf[4];
    #pragma unroll
    for (int a = 0; a < 4; a++)
      af[a] = *(const half8*)(As + fr * 1032 + (wm * 64 + a * 16 + fc) * 8);
    #pragma unroll
    for (int b = 0; b < 4; b++) {
      int col = wn * 64 + b * 16 + fc;
      bf[b] = *(const half8*)(Bs + (col >> 6) * 2048 + fr * 512 + (col & 63) * 8);
    }
    #pragma unroll
    for (int a = 0; a < 4; a++)
      #pragma unroll
      for (int b = 0; b < 4; b++)
        acc[a][b] = __builtin_amdgcn_mfma_f32_16x16x32_f16(af[a], bf[b], acc[a][b], 0, 0, 0);
    __syncthreads();
  }

  float* sval = (float*)smem;
  int*   sidx = (int*)(smem + 16384);
  #pragma unroll
  for (int a = 0; a < 4; a++) {
    #pragma unroll
    for (int rr = 0; rr < 4; rr++) {
      int rb = wm * 64 + a * 16 + fr * 4 + rr;
      float best = 1e30f; int bi = 0;
      #pragma unroll
      for (int b = 0; b < 4; b++) {
        int e = n0 + wn * 64 + b * 16 + fc;
        float s = ee[e] - 2.f * acc[a][b][rr];
        if (s < best) { best = s; bi = e; }
      }
      sval[rb * 32 + wn * 16 + fc] = best;
      sidx[rb * 32 + wn * 16 + fc] = bi;
    }
  }
  __syncthreads();
  if (tid < 128) {
    float best = sval[tid * 32]; int bi = sidx[tid * 32];
    for (int t = 1; t < 32; t++) {
      float v = sval[tid * 32 + t]; int ix = sidx[tid * 32 + t];
      if (v < best || (v == best && ix < bi)) { best = v; bi = ix; }
    }
    minval[(size_t)(m0 + tid) * 16 + blockIdx.y] = best;
    minidx[(size_t)(m0 + tid) * 16 + blockIdx.y] = bi;
  }
}

__global__ __launch_bounds__(256) void vq_finalize(const _Float16* __restrict__ h,
    const float* __restrict__ emb, const float* __restrict__ minval,
    const int* __restrict__ minidx, float* __restrict__ lossacc)
{
  const int tid = threadIdx.x;
  const int g = tid >> 4, l = tid & 15;
  const int v = blockIdx.x * 16 + g;
  float val = minval[(size_t)v * 16 + l];
  int   idx = minidx[(size_t)v * 16 + l];
  #pragma unroll
  for (int o = 8; o > 0; o >>= 1) {
    float v2 = __shfl_down(val, o, 16);
    int   i2 = __shfl_down(idx, o, 16);
    if (v2 < val || (v2 == val && i2 < idx)) { val = v2; idx = i2; }
  }
  idx = __shfl(idx, 0, 16);
  float s = 0.f;
  #pragma unroll
  for (int j = 0; j < 32; j++) {
    int c = l + 16 * j;
    float f = (float)h[(size_t)v * 512 + c];
    float e = emb[(size_t)idx * 512 + c];
    float dd = f - e;
    s += dd * dd;
  }
  #pragma unroll
  for (int o = 8; o > 0; o >>= 1) s += __shfl_down(s, o, 16);
  if (l == 0) atomicAdd(lossacc, s);
}

// ============================================================================
// BN apply with inline scale/shift derivation from fused stats (C >= 8)
// ============================================================================
__global__ __launch_bounds__(256) void bn_apply_inline(_Float16* __restrict__ y,
    const float2* __restrict__ stats, const float* __restrict__ g,
    const float* __restrict__ be, int Cs, int n8, float invM)
{
  const int C = 1 << Cs;
  __shared__ float scs[512], shs[512];
  for (int c = threadIdx.x; c < C; c += 256) {
    float s = 0.f, qv = 0.f;
    #pragma unroll
    for (int t = 0; t < STAT_SLOTS; t++) { float2 v = stats[c * STAT_SLOTS + t]; s += v.x; qv += v.y; }
    float m = s * invM, var = qv * invM - m * m;
    float sc = g[c] * rsqrtf(var + 1e-5f);
    scs[c] = sc; shs[c] = be[c] - m * sc;
  }
  __syncthreads();
  int i = blockIdx.x * 256 + threadIdx.x;
  if (i >= n8) return;
  int c0 = (i << 3) & (C - 1);
  half8 v = *(half8*)(y + (size_t)i * 8);
  half8 o;
  #pragma unroll
  for (int j = 0; j < 8; j++) {
    float x = (float)v[j] * scs[c0 + j] + shs[c0 + j];
    o[j] = (_Float16)(0.5f * x * (1.f + erff(x * 0.70710678118654752f)));
  }
  *(half8*)(y + (size_t)i * 8) = o;
}

__global__ __launch_bounds__(256) void bn_final_inline(const _Float16* __restrict__ y,
    float* __restrict__ out, const float2* __restrict__ stats,
    const float* __restrict__ g, const float* __restrict__ be,
    const float* __restrict__ lossacc)
{
  __shared__ float scs[4], shs[4];
  if (threadIdx.x < 3) {
    int c = threadIdx.x;
    float s = 0.f, qv = 0.f;
    #pragma unroll
    for (int t = 0; t < STAT_SLOTS; t++) { float2 v = stats[c * STAT_SLOTS + t]; s += v.x; qv += v.y; }
    const float invM = 1.f / 1048576.f;
    float m = s * invM, var = qv * invM - m * m;
    float sc = g[c] * rsqrtf(var + 1e-5f);
    scs[c] = sc; shs[c] = be[c] - m * sc;
  }
  __syncthreads();
  int p = blockIdx.x * 256 + threadIdx.x;
  int n = p >> 16, hw = p & 65535;
  half4t v = *(const half4t*)(y + (size_t)p * 4);
  #pragma unroll
  for (int c = 0; c < 3; c++) {
    float x = (float)v[c] * scs[c] + shs[c];
    float gg = 0.5f * x * (1.f + erff(x * 0.70710678118654752f));
    out[(size_t)(n * 3 + c) * 65536 + hw] = tanhf(gg);
  }
  if (p == 0) out[3145728] = lossacc[0] * (1.25f / 2097152.0f);
}

// ============================================================================
// layout transforms
// ============================================================================
__global__ __launch_bounds__(256) void im2col_enc0(const float* __restrict__ x,
                                                   _Float16* __restrict__ xp)
{
  int p = blockIdx.x * 256 + threadIdx.x;
  int n = p >> 14, oy = (p >> 7) & 127, ox = p & 127;
  const float* xb = x + (size_t)n * 3 * 65536;
  _Float16 v[32];
  #pragma unroll
  for (int k = 27; k < 32; k++) v[k] = (_Float16)0.f;
  #pragma unroll
  for (int tap = 0; tap < 9; tap++) {
    int kh = tap / 3, kw = tap - kh * 3;
    int ih = 2 * oy - 1 + kh, iw = 2 * ox - 1 + kw;
    bool ok = ((unsigned)ih < 256u) && ((unsigned)iw < 256u);
    #pragma unroll
    for (int c = 0; c < 3; c++)
      v[tap * 3 + c] = ok ? (_Float16)xb[(size_t)c * 65536 + ih * 256 + iw] : (_Float16)0.f;
  }
  _Float16* dst = xp + (size_t)p * 32;
  #pragma unroll
  for (int j = 0; j < 4; j++) *(half8*)(dst + j * 8) = *(half8*)(v + j * 8);
}

__global__ void wtrans0(const float* __restrict__ w, _Float16* __restrict__ wB)
{
  int idx = blockIdx.x * 256 + threadIdx.x;
  if (idx >= 2048) return;
  int k = idx >> 6, co = idx & 63;
  int tap = k / 3, c = k - tap * 3;
  float v = (k < 27) ? w[((size_t)co * 3 + c) * 9 + tap] : 0.f;
  int kg = (k >> 3) & 3, kj = k & 7;
  wB[kg * 512 + co * 8 + kj] = (_Float16)v;
}

__global__ void wtrans_n16_dec3(const float* __restrict__ w, _Float16* __restrict__ wB)
{
  int idx = blockIdx.x * 256 + threadIdx.x;
  if (idx >= 9216) return;
  int k = idx >> 4, co = idx & 15;
  int tap = k >> 6, ci = k & 63;
  float v = 0.f;
  if (co < 3) v = w[((size_t)ci * 3 + co) * 9 + tap];
  int kt = k >> 5, kg = (k >> 3) & 3, kj = k & 7;
  wB[(size_t)kt * 512 + kg * 128 + co * 8 + kj] = (_Float16)v;
}

__global__ __launch_bounds__(256) void wtrans(const float* __restrict__ w,
    _Float16* __restrict__ wB, int CIs, int CI_real, int COs, int CO_real, int is_dec)
{
  int idx = blockIdx.x * 256 + threadIdx.x;
  int CO_pad = 1 << COs;
  int K = 9 << CIs;
  if (idx >= K * CO_pad) return;
  int k = idx >> COs, co = idx & (CO_pad - 1);
  int tap = k >> CIs, ci = k & ((1 << CIs) - 1);
  int kh = tap / 3, kw = tap - kh * 3;
  float v = 0.f;
  if (ci < CI_real && co < CO_real)
    v = is_dec ? w[(((size_t)ci * CO_real + co) * 3 + kh) * 3 + kw]
               : w[(((size_t)co * CI_real + ci) * 3 + kh) * 3 + kw];
  int kt = k >> 5, kg = (k >> 3) & 3, kj = k & 7, jt = co >> 6, cc = co & 63;
  wB[(size_t)(kt * (CO_pad >> 6) + jt) * 2048 + kg * 512 + cc * 8 + kj] = (_Float16)v;
}

__global__ __launch_bounds__(256) void embtrans(const float* __restrict__ emb,
                                                _Float16* __restrict__ embB)
{
  int idx = blockIdx.x * 256 + threadIdx.x;
  int k = idx >> 11, e = idx & 2047;
  float v = emb[(size_t)e * 512 + k];
  int kt = k >> 5, kg = (k >> 3) & 3, kj = k & 7, jt = e >> 6, cc = e & 63;
  embB[(size_t)(kt * 32 + jt) * 2048 + kg * 512 + cc * 8 + kj] = (_Float16)v;
}

__global__ __launch_bounds__(256) void emb_norms(const float* __restrict__ emb,
                                                 float* __restrict__ ee)
{
  const int wv = threadIdx.x >> 6, lane = threadIdx.x & 63;
  const int e = blockIdx.x * 4 + wv;
  float s = 0.f;
  #pragma unroll
  for (int j = 0; j < 8; j++) { float v = emb[(size_t)e * 512 + lane + j * 64]; s += v * v; }
  for (int o = 32; o > 0; o >>= 1) s += __shfl_down(s, o);
  if (lane == 0) ee[e] = s;
}

__global__ __launch_bounds__(256) void zero_stats(float* __restrict__ p, int n)
{
  int i = blockIdx.x * 256 + threadIdx.x;
  if (i < n) p[i] = 0.f;
}

// ============================================================================
// host
// ============================================================================
static ConvDesc enc_desc(int HI, int WI, int CIs, int CO) {
  ConvDesc d = {};
  d.HI = HI; d.WI = WI; d.CIs = CIs;
  int HO = HI / 2, WO = WI / 2;
  d.OYs = __builtin_ctz(HO); d.OXs = __builtin_ctz(WO);
  d.SXY = 2; d.osxy = 1; d.HO = HO; d.WO = WO;
  d.CO_pad = CO; d.CO_real = CO; d.CO_store = CO;
  d.nclass = 1; d.py[0] = 0; d.px[0] = 0; d.nt[0] = 9;
  for (int t = 0; t < 9; t++) { d.tt[0][t] = t; d.tdy[0][t] = t / 3 - 1; d.tdx[0][t] = t % 3 - 1; }
  return d;
}

static ConvDesc dec_desc(int HI, int WI, int CIs, int CO_pad, int CO_real, int CO_store) {
  ConvDesc d = {};
  d.HI = HI; d.WI = WI; d.CIs = CIs;
  d.OYs = __builtin_ctz(HI); d.OXs = __builtin_ctz(WI);
  d.SXY = 1; d.osxy = 2; d.HO = 2 * HI; d.WO = 2 * WI;
  d.CO_pad = CO_pad; d.CO_real = CO_real; d.CO_store = CO_store;
  d.nclass = 4;
  int kys[2][2] = {{1, -1}, {0, 2}}, dis[2][2] = {{0, -1}, {1, 0}}, cnt[2] = {1, 2};
  for (int py = 0; py < 2; py++)
    for (int px = 0; px < 2; px++) {
      int c = py * 2 + px; d.py[c] = py; d.px[c] = px;
      int m = 0;
      for (int a = 0; a < cnt[py]; a++)
        for (int b = 0; b < cnt[px]; b++) {
          d.tt[c][m] = kys[py][a] * 3 + kys[px][b];
          d.tdy[c][m] = dis[py][a]; d.tdx[c][m] = dis[px][b]; m++;
        }
      d.nt[c] = m;
    }
  return d;
}

extern "C" void kernel_launch(void* const* d_in, const int* in_sizes, int n_in,
                              void* d_out, int out_size, void* d_ws, size_t ws_size,
                              hipStream_t stream)
{
  const float* x = (const float*)d_in[0];
  const float *ew[4], *ebi[4], *eg[4], *ebe[4];
  const float *dw[4], *dbi[4], *dg[4], *dbe[4];
  for (int i = 0; i < 4; i++) {
    ew[i]  = (const float*)d_in[1 + 4 * i];
    ebi[i] = (const float*)d_in[2 + 4 * i];
    eg[i]  = (const float*)d_in[3 + 4 * i];
    ebe[i] = (const float*)d_in[4 + 4 * i];
    dw[i]  = (const float*)d_in[17 + 4 * i];
    dbi[i] = (const float*)d_in[18 + 4 * i];
    dg[i]  = (const float*)d_in[19 + 4 * i];
    dbe[i] = (const float*)d_in[20 + 4 * i];
  }
  const float* emb = (const float*)d_in[33];
  float* out = (float*)d_out;
  _Float16* wsh = (_Float16*)d_ws;

  // memory map (halfs)
  _Float16* bufA = wsh;
  _Float16* xp   = wsh;
  _Float16* bufB = wsh + 33554432;
  size_t wboff = 50331648;
  _Float16* wbE[4], *wbD[4];
  size_t wbsz[8] = {18432, 73728, 294912, 1179648, 1179648, 294912, 73728, 36864};
  for (int i = 0; i < 4; i++) { wbE[i] = wsh + wboff; wboff += wbsz[i]; }
  for (int i = 0; i < 4; i++) { wbD[i] = wsh + wboff; wboff += wbsz[4 + i]; }
  _Float16* embB = wsh + wboff;               // ends 54,532,096
  float* f32 = (float*)(wsh + 54532096);
  // stats: 8 layers x 512ch x 16 slots x float2 = 131072 floats; lossacc right after
  float* statsAll = f32;
  float* lossacc  = f32 + 131072;
  float* ee       = f32 + 131080;
  float* minval   = f32 + 133128;
  int*   minidx   = (int*)(f32 + 198664);
  auto statsL = [&](int i) { return statsAll + (size_t)i * 16384; };

  // ---- transforms + stats zeroing ----
  zero_stats<<<513, 256, 0, stream>>>(statsAll, 131073);
  im2col_enc0<<<1024, 256, 0, stream>>>(x, xp);
  wtrans0<<<8, 256, 0, stream>>>(ew[0], wbE[0]);
  wtrans<<<288, 256, 0, stream>>>(ew[1], wbE[1], 6, 64, 7, 128, 0);
  wtrans<<<1152, 256, 0, stream>>>(ew[2], wbE[2], 7, 128, 8, 256, 0);
  wtrans<<<4608, 256, 0, stream>>>(ew[3], wbE[3], 8, 256, 9, 512, 0);
  wtrans<<<4608, 256, 0, stream>>>(dw[0], wbD[0], 9, 512, 8, 256, 1);
  wtrans<<<1152, 256, 0, stream>>>(dw[1], wbD[1], 8, 256, 7, 128, 1);
  wtrans<<<288, 256, 0, stream>>>(dw[2], wbD[2], 7, 128, 6, 64, 1);
  wtrans_n16_dec3<<<36, 256, 0, stream>>>(dw[3], wbD[3]);
  embtrans<<<4096, 256, 0, stream>>>(emb, embB);
  emb_norms<<<512, 256, 0, stream>>>(emb, ee);

  // ---- encoder ----
  {
    ConvDesc d = {};
    d.HI = 512; d.WI = 512; d.CIs = 5; d.OYs = 9; d.OXs = 9; d.SXY = 1; d.osxy = 1;
    d.HO = 512; d.WO = 512; d.CO_pad = 64; d.CO_real = 64; d.CO_store = 64;
    d.nclass = 1; d.nt[0] = 1;
    conv_gemm<128, 64><<<dim3(2048, 1, 1), 256, 0, stream>>>(xp, wbE[0], ebi[0], bufB, statsL(0), d);
    bn_apply_inline<<<8192, 256, 0, stream>>>(bufB, (const float2*)statsL(0), eg[0], ebe[0], 6, 2097152, 1.f / 262144.f);
  }
  {
    ConvDesc d = enc_desc(128, 128, 6, 128);
    conv_gemm<128, 128><<<dim3(512, 1, 1), 256, 0, stream>>>(bufB, wbE[1], ebi[1], bufA, statsL(1), d);
    bn_apply_inline<<<4096, 256, 0, stream>>>(bufA, (const float2*)statsL(1), eg[1], ebe[1], 7, 1048576, 1.f / 65536.f);
  }
  {
    ConvDesc d = enc_desc(64, 64, 7, 256);
    conv_gemm<128, 64><<<dim3(128, 4, 1), 256, 0, stream>>>(bufA, wbE[2], ebi[2], bufB, statsL(2), d);
    bn_apply_inline<<<2048, 256, 0, stream>>>(bufB, (const float2*)statsL(2), eg[2], ebe[2], 8, 524288, 1.f / 16384.f);
  }
  {
    ConvDesc d = enc_desc(32, 32, 8, 512);
    conv_gemm<64, 64><<<dim3(64, 8, 1), 256, 0, stream>>>(bufB, wbE[3], ebi[3], bufA, statsL(3), d);
    bn_apply_inline<<<1024, 256, 0, stream>>>(bufA, (const float2*)statsL(3), eg[3], ebe[3], 9, 262144, 1.f / 4096.f);
  }
  _Float16* h = bufA;  // (16,16,16,512) NHWC

  // ---- VQ ----
  vq_gemm<<<dim3(32, 16), 256, 0, stream>>>(h, embB, ee, minval, minidx);
  vq_finalize<<<256, 256, 0, stream>>>(h, emb, minval, minidx, lossacc);

  // ---- decoder ----
  {
    ConvDesc d = dec_desc(16, 16, 9, 256, 256, 256);
    conv_gemm<64, 64><<<dim3(64, 4, 4), 256, 0, stream>>>(h, wbD[0], dbi[0], bufB, statsL(4), d);
    bn_apply_inline<<<2048, 256, 0, stream>>>(bufB, (const float2*)statsL(4), dg[0], dbe[0], 8, 524288, 1.f / 16384.f);
  }
  {
    ConvDesc d = dec_desc(32, 32, 8, 128, 128, 128);
    conv_gemm<128, 128><<<dim3(128, 1, 4), 256, 0, stream>>>(bufB, wbD[1], dbi[1], bufA, statsL(5), d);
    bn_apply_inline<<<4096, 256, 0, stream>>>(bufA, (const float2*)statsL(5), dg[1], dbe[1], 7, 1048576, 1.f / 65536.f);
  }
  {
    ConvDesc d = dec_desc(64, 64, 7, 64, 64, 64);
    conv_gemm<128, 64><<<dim3(512, 1, 4), 256, 0, stream>>>(bufA, wbD[2], dbi[2], bufB, statsL(6), d);
    bn_apply_inline<<<8192, 256, 0, stream>>>(bufB, (const float2*)statsL(6), dg[2], dbe[2], 6, 2097152, 1.f / 262144.f);
  }
  {
    dec3_fused<<<1024, 256, 0, stream>>>(bufB, wbD[3], dbi[3], bufA, statsL(7));
    bn_final_inline<<<4096, 256, 0, stream>>>(bufA, out, (const float2*)statsL(7), dg[3], dbe[3], lossacc);
  }
}

// Round 11
// 649.780 us; speedup vs baseline: 1.4348x; 1.0711x over previous
//
#include <hip/hip_runtime.h>
#include <math.h>

typedef _Float16 half8 __attribute__((ext_vector_type(8)));
typedef _Float16 half4t __attribute__((ext_vector_type(4)));
typedef float floatx4 __attribute__((ext_vector_type(4)));

// ============================================================================
// ConvDesc
// ============================================================================
struct ConvDesc {
  int HI, WI;
  int CIs;
  int OYs, OXs;
  int SXY;
  int osxy;
  int HO, WO;
  int CO_pad, CO_real, CO_store;
  int nclass;
  int py[4], px[4], nt[4];
  int tt[4][9], tdy[4][9], tdx[4][9];
};

#define STAT_SLOTS 16

// ============================================================================
// conv_gemm<BM,BN>: dbuf K-loop + fused BN-stats epilogue.
// ============================================================================
template<int BM, int BN>
__global__ __launch_bounds__(256) void conv_gemm(
    const _Float16* __restrict__ act, const _Float16* __restrict__ wB,
    const float* __restrict__ bias, _Float16* __restrict__ y,
    float* __restrict__ stats, ConvDesc d)
{
  constexpr int WM = BM / 2, WN = BN / 2, FM = WM / 16, FN = WN / 16;
  constexpr int ARPT = BM / 64, BT = BN / 64;
  constexpr int AP = BM * 8 + 8;
  constexpr int ASZ = 4 * AP;
  constexpr int BSZ = BT * 2048;
  __shared__ __align__(16) _Float16 As[2 * ASZ];
  __shared__ __align__(16) _Float16 Bs[2 * BSZ];

  const int tid = threadIdx.x;
  const int cls = blockIdx.z;
  const int m0 = blockIdx.x * BM, n0 = blockIdx.y * BN;
  const int q = tid & 3, r0 = tid >> 2;

  int aih[ARPT], aiw[ARPT], abase[ARPT];
  #pragma unroll
  for (int i = 0; i < ARPT; i++) {
    int p = m0 + r0 + i * 64;
    int n  = p >> (d.OYs + d.OXs);
    int oy = (p >> d.OXs) & ((1 << d.OYs) - 1);
    int ox = p & ((1 << d.OXs) - 1);
    aih[i] = oy * d.SXY;
    aiw[i] = ox * d.SXY;
    abase[i] = n * d.HI;
  }

  floatx4 acc[FM][FN] = {};
  const int wv = tid >> 6, lane = tid & 63;
  const int wm = wv >> 1, wn = wv & 1;
  const int fr = lane >> 4, fc = lane & 15;
  const int c5s = d.CIs - 5;
  const int c5m = (1 << c5s) - 1;
  const int kiters = d.nt[cls] << c5s;

  auto stageK = [&](int kk, int buf) {
    int ti = kk >> c5s, c5 = kk & c5m;
    int dy = d.tdy[cls][ti], dx = d.tdx[cls][ti];
    int kt0 = d.tt[cls][ti] << c5s;
    int c0 = c5 << 5;
    #pragma unroll
    for (int i = 0; i < ARPT; i++) {
      int ih = aih[i] + dy, iw = aiw[i] + dx;
      half8 v = {};
      if ((unsigned)ih < (unsigned)d.HI && (unsigned)iw < (unsigned)d.WI)
        v = *(const half8*)(act + ((((size_t)(abase[i] + ih)) * d.WI + iw) << d.CIs) + c0 + q * 8);
      *(half8*)(As + buf * ASZ + q * AP + (r0 + i * 64) * 8) = v;
    }
    #pragma unroll
    for (int j = 0; j < BT; j++) {
      const _Float16* src = wB + (size_t)((kt0 + c5) * (d.CO_pad >> 6) + (n0 >> 6) + j) * 2048 + tid * 8;
      *(half8*)(Bs + buf * BSZ + j * 2048 + tid * 8) = *(const half8*)src;
    }
  };

  stageK(0, 0);
  for (int kk = 0; kk < kiters; kk++) {
    __syncthreads();
    if (kk + 1 < kiters) stageK(kk + 1, (kk + 1) & 1);
    const int buf = kk & 1;
    half8 af[FM], bf[FN];
    #pragma unroll
    for (int a = 0; a < FM; a++)
      af[a] = *(const half8*)(As + buf * ASZ + fr * AP + (wm * WM + a * 16 + fc) * 8);
    #pragma unroll
    for (int b = 0; b < FN; b++) {
      int col = wn * WN + b * 16 + fc;
      bf[b] = *(const half8*)(Bs + buf * BSZ + (col >> 6) * 2048 + fr * 512 + (col & 63) * 8);
    }
    #pragma unroll
    for (int a = 0; a < FM; a++)
      #pragma unroll
      for (int b = 0; b < FN; b++)
        acc[a][b] = __builtin_amdgcn_mfma_f32_16x16x32_f16(af[a], bf[b], acc[a][b], 0, 0, 0);
  }

  float bv[FN];
  int colg[FN];
  #pragma unroll
  for (int b = 0; b < FN; b++) {
    int col = n0 + wn * WN + b * 16 + fc;
    colg[b] = col;
    bv[b] = (col < d.CO_real) ? bias[col] : 0.f;
  }
  float ssum[FN] = {}, ssq[FN] = {};
  const int pyc = d.py[cls], pxc = d.px[cls];
  #pragma unroll
  for (int a = 0; a < FM; a++) {
    #pragma unroll
    for (int rr = 0; rr < 4; rr++) {
      int m = m0 + wm * WM + a * 16 + fr * 4 + rr;
      int n  = m >> (d.OYs + d.OXs);
      int oy = (m >> d.OXs) & ((1 << d.OYs) - 1);
      int ox = m & ((1 << d.OXs) - 1);
      size_t opix = ((size_t)(n * d.HO + oy * d.osxy + pyc)) * d.WO + ox * d.osxy + pxc;
      _Float16* dst = y + opix * d.CO_store;
      #pragma unroll
      for (int b = 0; b < FN; b++) {
        float val = acc[a][b][rr] + bv[b];
        if (colg[b] < d.CO_store) dst[colg[b]] = (_Float16)val;
        ssum[b] += val; ssq[b] += val * val;
      }
    }
  }

  __syncthreads();
  float2* red = (float2*)As;
  #pragma unroll
  for (int b = 0; b < FN; b++)
    red[(wn * WN + b * 16 + fc) * 8 + wm * 4 + fr] = make_float2(ssum[b], ssq[b]);
  __syncthreads();
  if (tid < BN) {
    float s = 0.f, qv = 0.f;
    #pragma unroll
    for (int g2 = 0; g2 < 8; g2++) { float2 v = red[tid * 8 + g2]; s += v.x; qv += v.y; }
    int slot = (blockIdx.x + blockIdx.z) & (STAT_SLOTS - 1);
    float* sp = stats + ((size_t)(n0 + tid) * STAT_SLOTS + slot) * 2;
    atomicAdd(sp, s); atomicAdd(sp + 1, qv);
  }
}

// ============================================================================
// dec2_fused: ConvT 128ch -> 64ch, input (16,64,64,128), output (16,128,128,64).
// One block = 1 input row (64 px); 2x66 halo staged once per 32-ch chunk in
// LDS; all 9 taps / 4 parity classes served from it. B (9 taps x 4KB) staged
// per chunk from L2-resident weights. Fused BN-stats epilogue.
// ============================================================================
__global__ __launch_bounds__(256) void dec2_fused(
    const _Float16* __restrict__ act, const _Float16* __restrict__ wB,
    const float* __restrict__ bias, _Float16* __restrict__ y,
    float* __restrict__ stats)
{
  __shared__ __align__(16) _Float16 As[4 * 1056];   // [kg4][slot 2*66][8]
  __shared__ __align__(16) _Float16 Bs[18432];      // [t9][kg4][cc64][kj8]
  const int tid = threadIdx.x;
  const int n = blockIdx.x >> 6;
  const int R = blockIdx.x & 63;
  const int wv = tid >> 6, lane = tid & 63;
  const int fr = lane >> 4, fc = lane & 15;

  floatx4 acc[4][4] = {};   // [cls][b]

  for (int c5 = 0; c5 < 4; c5++) {
    __syncthreads();
    for (int i = tid; i < 528; i += 256) {
      int slot = i >> 2, q = i & 3;
      int hr = slot / 66, hc = slot - hr * 66;
      int grow = R + hr;
      half8 v = {};
      if (grow < 64 && hc < 64)
        v = *(const half8*)(act + (((size_t)(n * 64 + grow)) * 64 + hc) * 128 + c5 * 32 + q * 8);
      *(half8*)(As + q * 1056 + slot * 8) = v;
    }
    #pragma unroll
    for (int t = 0; t < 9; t++)
      *(half8*)(Bs + t * 2048 + tid * 8) =
          *(const half8*)(wB + (size_t)(t * 4 + c5) * 2048 + tid * 8);
    __syncthreads();
    #pragma unroll
    for (int t = 0; t < 9; t++) {
      const int ky = t / 3, kx = t % 3;
      const int dy = (ky == 0) ? 1 : 0, dx = (kx == 0) ? 1 : 0;
      const int cls = ((ky + 1) & 1) * 2 + ((kx + 1) & 1);
      half8 af = *(const half8*)(As + fr * 1056 + (dy * 66 + wv * 16 + fc + dx) * 8);
      #pragma unroll
      for (int b = 0; b < 4; b++) {
        half8 bf = *(const half8*)(Bs + t * 2048 + fr * 512 + (b * 16 + fc) * 8);
        acc[cls][b] = __builtin_amdgcn_mfma_f32_16x16x32_f16(af, bf, acc[cls][b], 0, 0, 0);
      }
    }
  }

  float bv[4];
  #pragma unroll
  for (int b = 0; b < 4; b++) bv[b] = bias[b * 16 + fc];
  float ssum[4] = {}, ssq[4] = {};
  #pragma unroll
  for (int cls = 0; cls < 4; cls++) {
    int py = cls >> 1, px = cls & 1;
    int orow = 2 * R + py;
    #pragma unroll
    for (int b = 0; b < 4; b++) {
      #pragma unroll
      for (int rr = 0; rr < 4; rr++) {
        int ipx = wv * 16 + fr * 4 + rr;
        size_t opix = ((size_t)(n * 128 + orow)) * 128 + 2 * ipx + px;
        float val = acc[cls][b][rr] + bv[b];
        y[opix * 64 + b * 16 + fc] = (_Float16)val;
        ssum[b] += val; ssq[b] += val * val;
      }
    }
  }
  __syncthreads();
  float2* red = (float2*)As;   // 64 ch x 16 groups = 8KB
  #pragma unroll
  for (int b = 0; b < 4; b++)
    red[(b * 16 + fc) * 16 + wv * 4 + fr] = make_float2(ssum[b], ssq[b]);
  __syncthreads();
  if (tid < 64) {
    float s = 0.f, qv = 0.f;
    #pragma unroll
    for (int g2 = 0; g2 < 16; g2++) { float2 v = red[tid * 16 + g2]; s += v.x; qv += v.y; }
    int slot = blockIdx.x & (STAT_SLOTS - 1);
    float* sp = stats + ((size_t)tid * STAT_SLOTS + slot) * 2;
    atomicAdd(sp, s); atomicAdd(sp + 1, qv);
  }
}

// ============================================================================
// dec3_fused: ConvT 64ch -> 4ch (real 3) + fused stats epilogue.
// ============================================================================
__global__ __launch_bounds__(256) void dec3_fused(
    const _Float16* __restrict__ act, const _Float16* __restrict__ wB,
    const float* __restrict__ bias, _Float16* __restrict__ y,
    float* __restrict__ stats)
{
  __shared__ __align__(16) _Float16 As[4 * 3168];
  __shared__ __align__(16) _Float16 Bs[9216];
  const int tid = threadIdx.x;
  const int n = blockIdx.x >> 6;
  const int y0 = (blockIdx.x & 63) << 1;
  const int wv = tid >> 6, lane = tid & 63;
  const int fr = lane >> 4, fc = lane & 15;

  for (int i = tid; i < 1152; i += 256)
    *(half8*)(Bs + i * 8) = *(const half8*)(wB + i * 8);

  floatx4 acc[4][4] = {};

  for (int c5 = 0; c5 < 2; c5++) {
    __syncthreads();
    for (int i = tid; i < 1584; i += 256) {
      int slot = i >> 2, q = i & 3;
      int prow = slot / 132, pcol = slot - prow * 132;
      int row = y0 + prow;
      half8 v = {};
      if (row < 128 && pcol < 128)
        v = *(const half8*)(act + (((size_t)(n * 128 + row)) * 128 + pcol) * 64 + c5 * 32 + q * 8);
      *(half8*)(As + q * 3168 + slot * 8) = v;
    }
    __syncthreads();
    #pragma unroll
    for (int t = 0; t < 9; t++) {
      const int ky = t / 3, kx = t % 3;
      const int dy = (ky == 0) ? 1 : 0, dx = (kx == 0) ? 1 : 0;
      const int cls = ((ky + 1) & 1) * 2 + ((kx + 1) & 1);
      half8 bf = *(const half8*)(Bs + (t * 2 + c5) * 512 + fr * 128 + fc * 8);
      #pragma unroll
      for (int a = 0; a < 4; a++) {
        int m = wv * 64 + a * 16 + fc;
        int r = m >> 7, xx = m & 127;
        half8 af = *(const half8*)(As + fr * 3168 + ((r + dy) * 132 + xx + dx) * 8);
        acc[cls][a] = __builtin_amdgcn_mfma_f32_16x16x32_f16(af, bf, acc[cls][a], 0, 0, 0);
      }
    }
  }

  float bv = (fc < 3) ? bias[fc] : 0.f;
  float s4 = 0.f, q4 = 0.f;
  if (fc < 4) {
    #pragma unroll
    for (int cls = 0; cls < 4; cls++) {
      int py = cls >> 1, px = cls & 1;
      #pragma unroll
      for (int a = 0; a < 4; a++) {
        #pragma unroll
        for (int rr = 0; rr < 4; rr++) {
          int m = wv * 64 + a * 16 + fr * 4 + rr;
          int r = m >> 7, xx = m & 127;
          size_t opix = ((size_t)(n * 256 + (y0 + r) * 2 + py)) * 256 + xx * 2 + px;
          float val = acc[cls][a][rr] + bv;
          y[opix * 4 + fc] = (_Float16)val;
          s4 += val; q4 += val * val;
        }
      }
    }
  }
  __syncthreads();
  float2* red = (float2*)As;
  if (fc < 4) red[fc * 16 + wv * 4 + fr] = make_float2(s4, q4);
  __syncthreads();
  if (tid < 4) {
    float s = 0.f, qv = 0.f;
    #pragma unroll
    for (int g2 = 0; g2 < 16; g2++) { float2 v = red[tid * 16 + g2]; s += v.x; qv += v.y; }
    int slot = blockIdx.x & (STAT_SLOTS - 1);
    float* sp = stats + ((size_t)tid * STAT_SLOTS + slot) * 2;
    atomicAdd(sp, s); atomicAdd(sp + 1, qv);
  }
}

// ============================================================================
// VQ GEMM
// ============================================================================
__global__ __launch_bounds__(256) void vq_gemm(const _Float16* __restrict__ h,
    const _Float16* __restrict__ embB, const float* __restrict__ ee,
    float* __restrict__ minval, int* __restrict__ minidx)
{
  __shared__ char smem[32768];
  _Float16* As = (_Float16*)smem;
  _Float16* Bs = (_Float16*)(smem + 8448);
  const int tid = threadIdx.x;
  const int m0 = blockIdx.x * 128, n0 = blockIdx.y * 128;
  const int q = tid & 3, r0 = tid >> 2;
  floatx4 acc[4][4] = {};
  const int wv = tid >> 6, lane = tid & 63;
  const int wm = wv >> 1, wn = wv & 1;
  const int fr = lane >> 4, fc = lane & 15;

  for (int c5 = 0; c5 < 16; c5++) {
    #pragma unroll
    for (int i = 0; i < 2; i++) {
      half8 v = *(const half8*)(h + (size_t)(m0 + r0 + i * 64) * 512 + c5 * 32 + q * 8);
      *(half8*)(As + q * 1032 + (r0 + i * 64) * 8) = v;
    }
    #pragma unroll
    for (int j = 0; j < 2; j++)
      *(half8*)(Bs + j * 2048 + tid * 8) =
          *(const half8*)(embB + (size_t)(c5 * 32 + (n0 >> 6) + j) * 2048 + tid * 8);
    __syncthreads();
    half8 af[4], bf[4];
    #pragma unroll
    for (int a = 0; a < 4; a++)
      af[a] = *(const half8*)(As + fr * 1032 + (wm * 64 + a * 16 + fc) * 8);
    #pragma unroll
    for (int b = 0; b < 4; b++) {
      int col = wn * 64 + b * 16 + fc;
      bf[b] = *(const half8*)(Bs + (col >> 6) * 2048 + fr * 512 + (col & 63) * 8);
    }
    #pragma unroll
    for (int a = 0; a < 4; a++)
      #pragma unroll
      for (int b = 0; b < 4; b++)
        acc[a][b] = __builtin_amdgcn_mfma_f32_16x16x32_f16(af[a], bf[b], acc[a][b], 0, 0, 0);
    __syncthreads();
  }

  float* sval = (float*)smem;
  int*   sidx = (int*)(smem + 16384);
  #pragma unroll
  for (int a = 0; a < 4; a++) {
    #pragma unroll
    for (int rr = 0; rr < 4; rr++) {
      int rb = wm * 64 + a * 16 + fr * 4 + rr;
      float best = 1e30f; int bi = 0;
      #pragma unroll
      for (int b = 0; b < 4; b++) {
        int e = n0 + wn * 64 + b * 16 + fc;
        float s = ee[e] - 2.f * acc[a][b][rr];
        if (s < best) { best = s; bi = e; }
      }
      sval[rb * 32 + wn * 16 + fc] = best;
      sidx[rb * 32 + wn * 16 + fc] = bi;
    }
  }
  __syncthreads();
  if (tid < 128) {
    float best = sval[tid * 32]; int bi = sidx[tid * 32];
    for (int t = 1; t < 32; t++) {
      float v = sval[tid * 32 + t]; int ix = sidx[tid * 32 + t];
      if (v < best || (v == best && ix < bi)) { best = v; bi = ix; }
    }
    minval[(size_t)(m0 + tid) * 16 + blockIdx.y] = best;
    minidx[(size_t)(m0 + tid) * 16 + blockIdx.y] = bi;
  }
}

__global__ __launch_bounds__(256) void vq_finalize(const _Float16* __restrict__ h,
    const float* __restrict__ emb, const float* __restrict__ minval,
    const int* __restrict__ minidx, float* __restrict__ lossacc)
{
  const int tid = threadIdx.x;
  const int g = tid >> 4, l = tid & 15;
  const int v = blockIdx.x * 16 + g;
  float val = minval[(size_t)v * 16 + l];
  int   idx = minidx[(size_t)v * 16 + l];
  #pragma unroll
  for (int o = 8; o > 0; o >>= 1) {
    float v2 = __shfl_down(val, o, 16);
    int   i2 = __shfl_down(idx, o, 16);
    if (v2 < val || (v2 == val && i2 < idx)) { val = v2; idx = i2; }
  }
  idx = __shfl(idx, 0, 16);
  float s = 0.f;
  #pragma unroll
  for (int j = 0; j < 32; j++) {
    int c = l + 16 * j;
    float f = (float)h[(size_t)v * 512 + c];
    float e = emb[(size_t)idx * 512 + c];
    float dd = f - e;
    s += dd * dd;
  }
  #pragma unroll
  for (int o = 8; o > 0; o >>= 1) s += __shfl_down(s, o, 16);
  if (l == 0) atomicAdd(lossacc, s);
}

// ============================================================================
// BN apply with inline scale/shift derivation from fused stats
// ============================================================================
__global__ __launch_bounds__(256) void bn_apply_inline(_Float16* __restrict__ y,
    const float2* __restrict__ stats, const float* __restrict__ g,
    const float* __restrict__ be, int Cs, int n8, float invM)
{
  const int C = 1 << Cs;
  __shared__ float scs[512], shs[512];
  for (int c = threadIdx.x; c < C; c += 256) {
    float s = 0.f, qv = 0.f;
    #pragma unroll
    for (int t = 0; t < STAT_SLOTS; t++) { float2 v = stats[c * STAT_SLOTS + t]; s += v.x; qv += v.y; }
    float m = s * invM, var = qv * invM - m * m;
    float sc = g[c] * rsqrtf(var + 1e-5f);
    scs[c] = sc; shs[c] = be[c] - m * sc;
  }
  __syncthreads();
  int i = blockIdx.x * 256 + threadIdx.x;
  if (i >= n8) return;
  int c0 = (i << 3) & (C - 1);
  half8 v = *(half8*)(y + (size_t)i * 8);
  half8 o;
  #pragma unroll
  for (int j = 0; j < 8; j++) {
    float x = (float)v[j] * scs[c0 + j] + shs[c0 + j];
    o[j] = (_Float16)(0.5f * x * (1.f + erff(x * 0.70710678118654752f)));
  }
  *(half8*)(y + (size_t)i * 8) = o;
}

__global__ __launch_bounds__(256) void bn_final_inline(const _Float16* __restrict__ y,
    float* __restrict__ out, const float2* __restrict__ stats,
    const float* __restrict__ g, const float* __restrict__ be,
    const float* __restrict__ lossacc)
{
  __shared__ float scs[4], shs[4];
  if (threadIdx.x < 3) {
    int c = threadIdx.x;
    float s = 0.f, qv = 0.f;
    #pragma unroll
    for (int t = 0; t < STAT_SLOTS; t++) { float2 v = stats[c * STAT_SLOTS + t]; s += v.x; qv += v.y; }
    const float invM = 1.f / 1048576.f;
    float m = s * invM, var = qv * invM - m * m;
    float sc = g[c] * rsqrtf(var + 1e-5f);
    scs[c] = sc; shs[c] = be[c] - m * sc;
  }
  __syncthreads();
  int p = blockIdx.x * 256 + threadIdx.x;
  int n = p >> 16, hw = p & 65535;
  half4t v = *(const half4t*)(y + (size_t)p * 4);
  #pragma unroll
  for (int c = 0; c < 3; c++) {
    float x = (float)v[c] * scs[c] + shs[c];
    float gg = 0.5f * x * (1.f + erff(x * 0.70710678118654752f));
    out[(size_t)(n * 3 + c) * 65536 + hw] = tanhf(gg);
  }
  if (p == 0) out[3145728] = lossacc[0] * (1.25f / 2097152.0f);
}

// ============================================================================
// prep_all: single kernel for every once-per-launch transform.
// Segments (hard-coded block offsets):
//  [0,8) enc0 w | [8,296) enc1 | [296,1448) enc2 | [1448,6056) enc3
//  [6056,10664) dec0 | [10664,11816) dec1 | [11816,12104) dec2
//  [12104,12140) dec3_n16 | [12140,16236) embtrans | [16236,16749) zero stats
//  [16749,17261) emb_norms | [17261,18285) im2col
// ============================================================================
struct PrepPtrs {
  const float *ew0, *ew1, *ew2, *ew3, *dw0, *dw1, *dw2, *dw3, *emb, *x;
  _Float16 *wbE0, *wbE1, *wbE2, *wbE3, *wbD0, *wbD1, *wbD2, *wbD3, *embB, *xp;
  float *ee, *stats;
};

__device__ __forceinline__ void wtrans_g(const float* __restrict__ w,
    _Float16* __restrict__ wB, int CIs, int CI_real, int COs, int CO_real,
    int is_dec, int idx)
{
  int CO_pad = 1 << COs;
  int k = idx >> COs, co = idx & (CO_pad - 1);
  int tap = k >> CIs, ci = k & ((1 << CIs) - 1);
  int kh = tap / 3, kw = tap - kh * 3;
  float v = 0.f;
  if (ci < CI_real && co < CO_real)
    v = is_dec ? w[(((size_t)ci * CO_real + co) * 3 + kh) * 3 + kw]
               : w[(((size_t)co * CI_real + ci) * 3 + kh) * 3 + kw];
  int kt = k >> 5, kg = (k >> 3) & 3, kj = k & 7, jt = co >> 6, cc = co & 63;
  wB[(size_t)(kt * (CO_pad >> 6) + jt) * 2048 + kg * 512 + cc * 8 + kj] = (_Float16)v;
}

__global__ __launch_bounds__(256) void prep_all(PrepPtrs P)
{
  const int b = blockIdx.x;
  const int tid = threadIdx.x;
  if (b < 8) {                         // enc0 weights: K=32, tap*3+c
    int idx = b * 256 + tid;
    int k = idx >> 6, co = idx & 63;
    int tap = k / 3, c = k - tap * 3;
    float v = (k < 27) ? P.ew0[((size_t)co * 3 + c) * 9 + tap] : 0.f;
    int kg = (k >> 3) & 3, kj = k & 7;
    P.wbE0[kg * 512 + co * 8 + kj] = (_Float16)v;
  } else if (b < 296) {
    wtrans_g(P.ew1, P.wbE1, 6, 64, 7, 128, 0, (b - 8) * 256 + tid);
  } else if (b < 1448) {
    wtrans_g(P.ew2, P.wbE2, 7, 128, 8, 256, 0, (b - 296) * 256 + tid);
  } else if (b < 6056) {
    wtrans_g(P.ew3, P.wbE3, 8, 256, 9, 512, 0, (b - 1448) * 256 + tid);
  } else if (b < 10664) {
    wtrans_g(P.dw0, P.wbD0, 9, 512, 8, 256, 1, (b - 6056) * 256 + tid);
  } else if (b < 11816) {
    wtrans_g(P.dw1, P.wbD1, 8, 256, 7, 128, 1, (b - 10664) * 256 + tid);
  } else if (b < 12104) {
    wtrans_g(P.dw2, P.wbD2, 7, 128, 6, 64, 1, (b - 11816) * 256 + tid);
  } else if (b < 12140) {              // dec3 16-col tiles, no flip
    int idx = (b - 12104) * 256 + tid;
    int k = idx >> 4, co = idx & 15;
    int tap = k >> 6, ci = k & 63;
    float v = 0.f;
    if (co < 3) v = P.dw3[((size_t)ci * 3 + co) * 9 + tap];
    int kt = k >> 5, kg = (k >> 3) & 3, kj = k & 7;
    P.wbD3[(size_t)kt * 512 + kg * 128 + co * 8 + kj] = (_Float16)v;
  } else if (b < 16236) {              // embtrans
    int idx = (b - 12140) * 256 + tid;
    int k = idx >> 11, e = idx & 2047;
    float v = P.emb[(size_t)e * 512 + k];
    int kt = k >> 5, kg = (k >> 3) & 3, kj = k & 7, jt = e >> 6, cc = e & 63;
    P.embB[(size_t)(kt * 32 + jt) * 2048 + kg * 512 + cc * 8 + kj] = (_Float16)v;
  } else if (b < 16749) {              // zero stats (+lossacc)
    int i = (b - 16236) * 256 + tid;
    if (i < 131073) P.stats[i] = 0.f;
  } else if (b < 17261) {              // emb norms
    int wv = tid >> 6, lane = tid & 63;
    int e = (b - 16749) * 4 + wv;
    float s = 0.f;
    #pragma unroll
    for (int j = 0; j < 8; j++) { float v = P.emb[(size_t)e * 512 + lane + j * 64]; s += v * v; }
    for (int o = 32; o > 0; o >>= 1) s += __shfl_down(s, o);
    if (lane == 0) P.ee[e] = s;
  } else {                             // im2col enc0
    int p = (b - 17261) * 256 + tid;
    int n = p >> 14, oy = (p >> 7) & 127, ox = p & 127;
    const float* xb = P.x + (size_t)n * 3 * 65536;
    _Float16 v[32];
    #pragma unroll
    for (int k = 27; k < 32; k++) v[k] = (_Float16)0.f;
    #pragma unroll
    for (int tap = 0; tap < 9; tap++) {
      int kh = tap / 3, kw = tap - kh * 3;
      int ih = 2 * oy - 1 + kh, iw = 2 * ox - 1 + kw;
      bool ok = ((unsigned)ih < 256u) && ((unsigned)iw < 256u);
      #pragma unroll
      for (int c = 0; c < 3; c++)
        v[tap * 3 + c] = ok ? (_Float16)xb[(size_t)c * 65536 + ih * 256 + iw] : (_Float16)0.f;
    }
    _Float16* dst = P.xp + (size_t)p * 32;
    #pragma unroll
    for (int j = 0; j < 4; j++) *(half8*)(dst + j * 8) = *(half8*)(v + j * 8);
  }
}

// ============================================================================
// host
// ============================================================================
static ConvDesc enc_desc(int HI, int WI, int CIs, int CO) {
  ConvDesc d = {};
  d.HI = HI; d.WI = WI; d.CIs = CIs;
  int HO = HI / 2, WO = WI / 2;
  d.OYs = __builtin_ctz(HO); d.OXs = __builtin_ctz(WO);
  d.SXY = 2; d.osxy = 1; d.HO = HO; d.WO = WO;
  d.CO_pad = CO; d.CO_real = CO; d.CO_store = CO;
  d.nclass = 1; d.py[0] = 0; d.px[0] = 0; d.nt[0] = 9;
  for (int t = 0; t < 9; t++) { d.tt[0][t] = t; d.tdy[0][t] = t / 3 - 1; d.tdx[0][t] = t % 3 - 1; }
  return d;
}

static ConvDesc dec_desc(int HI, int WI, int CIs, int CO_pad, int CO_real, int CO_store) {
  ConvDesc d = {};
  d.HI = HI; d.WI = WI; d.CIs = CIs;
  d.OYs = __builtin_ctz(HI); d.OXs = __builtin_ctz(WI);
  d.SXY = 1; d.osxy = 2; d.HO = 2 * HI; d.WO = 2 * WI;
  d.CO_pad = CO_pad; d.CO_real = CO_real; d.CO_store = CO_store;
  d.nclass = 4;
  int kys[2][2] = {{1, -1}, {0, 2}}, dis[2][2] = {{0, -1}, {1, 0}}, cnt[2] = {1, 2};
  for (int py = 0; py < 2; py++)
    for (int px = 0; px < 2; px++) {
      int c = py * 2 + px; d.py[c] = py; d.px[c] = px;
      int m = 0;
      for (int a = 0; a < cnt[py]; a++)
        for (int b = 0; b < cnt[px]; b++) {
          d.tt[c][m] = kys[py][a] * 3 + kys[px][b];
          d.tdy[c][m] = dis[py][a]; d.tdx[c][m] = dis[px][b]; m++;
        }
      d.nt[c] = m;
    }
  return d;
}

extern "C" void kernel_launch(void* const* d_in, const int* in_sizes, int n_in,
                              void* d_out, int out_size, void* d_ws, size_t ws_size,
                              hipStream_t stream)
{
  const float* x = (const float*)d_in[0];
  const float *ew[4], *ebi[4], *eg[4], *ebe[4];
  const float *dw[4], *dbi[4], *dg[4], *dbe[4];
  for (int i = 0; i < 4; i++) {
    ew[i]  = (const float*)d_in[1 + 4 * i];
    ebi[i] = (const float*)d_in[2 + 4 * i];
    eg[i]  = (const float*)d_in[3 + 4 * i];
    ebe[i] = (const float*)d_in[4 + 4 * i];
    dw[i]  = (const float*)d_in[17 + 4 * i];
    dbi[i] = (const float*)d_in[18 + 4 * i];
    dg[i]  = (const float*)d_in[19 + 4 * i];
    dbe[i] = (const float*)d_in[20 + 4 * i];
  }
  const float* emb = (const float*)d_in[33];
  float* out = (float*)d_out;
  _Float16* wsh = (_Float16*)d_ws;

  // memory map (halfs)
  _Float16* bufA = wsh;
  _Float16* xp   = wsh;
  _Float16* bufB = wsh + 33554432;
  size_t wboff = 50331648;
  _Float16* wbE[4], *wbD[4];
  size_t wbsz[8] = {18432, 73728, 294912, 1179648, 1179648, 294912, 73728, 36864};
  for (int i = 0; i < 4; i++) { wbE[i] = wsh + wboff; wboff += wbsz[i]; }
  for (int i = 0; i < 4; i++) { wbD[i] = wsh + wboff; wboff += wbsz[4 + i]; }
  _Float16* embB = wsh + wboff;               // ends 54,532,096
  float* f32 = (float*)(wsh + 54532096);
  float* statsAll = f32;                      // 8 x 16384 floats
  float* lossacc  = f32 + 131072;
  float* ee       = f32 + 131080;
  float* minval   = f32 + 133128;
  int*   minidx   = (int*)(f32 + 198664);
  auto statsL = [&](int i) { return statsAll + (size_t)i * 16384; };

  // ---- single prep kernel ----
  PrepPtrs P;
  P.ew0 = ew[0]; P.ew1 = ew[1]; P.ew2 = ew[2]; P.ew3 = ew[3];
  P.dw0 = dw[0]; P.dw1 = dw[1]; P.dw2 = dw[2]; P.dw3 = dw[3];
  P.emb = emb; P.x = x;
  P.wbE0 = wbE[0]; P.wbE1 = wbE[1]; P.wbE2 = wbE[2]; P.wbE3 = wbE[3];
  P.wbD0 = wbD[0]; P.wbD1 = wbD[1]; P.wbD2 = wbD[2]; P.wbD3 = wbD[3];
  P.embB = embB; P.xp = xp; P.ee = ee; P.stats = statsAll;
  prep_all<<<18285, 256, 0, stream>>>(P);

  // ---- encoder ----
  {
    ConvDesc d = {};
    d.HI = 512; d.WI = 512; d.CIs = 5; d.OYs = 9; d.OXs = 9; d.SXY = 1; d.osxy = 1;
    d.HO = 512; d.WO = 512; d.CO_pad = 64; d.CO_real = 64; d.CO_store = 64;
    d.nclass = 1; d.nt[0] = 1;
    conv_gemm<128, 64><<<dim3(2048, 1, 1), 256, 0, stream>>>(xp, wbE[0], ebi[0], bufB, statsL(0), d);
    bn_apply_inline<<<8192, 256, 0, stream>>>(bufB, (const float2*)statsL(0), eg[0], ebe[0], 6, 2097152, 1.f / 262144.f);
  }
  {
    ConvDesc d = enc_desc(128, 128, 6, 128);
    conv_gemm<128, 128><<<dim3(512, 1, 1), 256, 0, stream>>>(bufB, wbE[1], ebi[1], bufA, statsL(1), d);
    bn_apply_inline<<<4096, 256, 0, stream>>>(bufA, (const float2*)statsL(1), eg[1], ebe[1], 7, 1048576, 1.f / 65536.f);
  }
  {
    ConvDesc d = enc_desc(64, 64, 7, 256);
    conv_gemm<128, 64><<<dim3(128, 4, 1), 256, 0, stream>>>(bufA, wbE[2], ebi[2], bufB, statsL(2), d);
    bn_apply_inline<<<2048, 256, 0, stream>>>(bufB, (const float2*)statsL(2), eg[2], ebe[2], 8, 524288, 1.f / 16384.f);
  }
  {
    ConvDesc d = enc_desc(32, 32, 8, 512);
    conv_gemm<64, 64><<<dim3(64, 8, 1), 256, 0, stream>>>(bufB, wbE[3], ebi[3], bufA, statsL(3), d);
    bn_apply_inline<<<1024, 256, 0, stream>>>(bufA, (const float2*)statsL(3), eg[3], ebe[3], 9, 262144, 1.f / 4096.f);
  }
  _Float16* h = bufA;  // (16,16,16,512) NHWC

  // ---- VQ ----
  vq_gemm<<<dim3(32, 16), 256, 0, stream>>>(h, embB, ee, minval, minidx);
  vq_finalize<<<256, 256, 0, stream>>>(h, emb, minval, minidx, lossacc);

  // ---- decoder ----
  {
    ConvDesc d = dec_desc(16, 16, 9, 256, 256, 256);
    conv_gemm<64, 64><<<dim3(64, 4, 4), 256, 0, stream>>>(h, wbD[0], dbi[0], bufB, statsL(4), d);
    bn_apply_inline<<<2048, 256, 0, stream>>>(bufB, (const float2*)statsL(4), dg[0], dbe[0], 8, 524288, 1.f / 16384.f);
  }
  {
    ConvDesc d = dec_desc(32, 32, 8, 128, 128, 128);
    conv_gemm<128, 128><<<dim3(128, 1, 4), 256, 0, stream>>>(bufB, wbD[1], dbi[1], bufA, statsL(5), d);
    bn_apply_inline<<<4096, 256, 0, stream>>>(bufA, (const float2*)statsL(5), dg[1], dbe[1], 7, 1048576, 1.f / 65536.f);
  }
  {
    dec2_fused<<<1024, 256, 0, stream>>>(bufA, wbD[2], dbi[2], bufB, statsL(6));
    bn_apply_inline<<<8192, 256, 0, stream>>>(bufB, (const float2*)statsL(6), dg[2], dbe[2], 6, 2097152, 1.f / 262144.f);
  }
  {
    dec3_fused<<<1024, 256, 0, stream>>>(bufB, wbD[3], dbi[3], bufA, statsL(7));
    bn_final_inline<<<4096, 256, 0, stream>>>(bufA, out, (const float2*)statsL(7), dg[3], dbe[3], lossacc);
  }
}